// Round 14
// baseline (303.393 us; speedup 1.0000x reference)
//
#include <hip/hip_runtime.h>
#include <hip/hip_bf16.h>

#define B 4
#define H 480
#define W 640
#define HW (H*W)
#define BHW (B*H*W)
#define NKP 1024
#define THRESH 0.005f
#define CAP 16384
#define NCOL (B*NKP)
#define KTOT 704

typedef __attribute__((ext_vector_type(8))) short s8v;
typedef __attribute__((ext_vector_type(4))) float f4v;
typedef struct { float x, y; } __attribute__((aligned(4))) f2u;   // 4B-aligned pair load

__device__ __forceinline__ short f2bf(float f) {
    __hip_bfloat16 h = __float2bfloat16(f);
    return *(short*)&h;
}
__device__ __forceinline__ float bf2f(short s) {
    unsigned u = ((unsigned)(unsigned short)s) << 16;   // exact bf16 -> f32
    return __uint_as_float(u);
}

__device__ __forceinline__ float max3f(float a, float b, float c) {
    return fmaxf(fmaxf(a, b), c);     // clang fuses to v_max3_f32
}
// 9-wide max as a depth-2 tree of v_max3_f32 (4 instrs vs 8-deep chain)
#define MAX9(A, base, str) \
    max3f(max3f((A)[(base)], (A)[(base)+(str)], (A)[(base)+2*(str)]), \
          max3f((A)[(base)+3*(str)], (A)[(base)+4*(str)], (A)[(base)+5*(str)]), \
          max3f((A)[(base)+6*(str)], (A)[(base)+7*(str)], (A)[(base)+8*(str)]))

// ===== fuse_w: Mw[256,704] weight fold; block=(64 cols x 4 K-slice waves) =====
__global__ __launch_bounds__(256) void fuse_w(const float* __restrict__ merge_w,
                                              const float* __restrict__ lin0_w,
                                              const float* __restrict__ lin1_w,
                                              const float* __restrict__ lin2_w,
                                              short* __restrict__ Mw) {
    __shared__ float red[4][64];
    int lane = threadIdx.x & 63;
    int wv = threadIdx.x >> 6;
    int jb = blockIdx.x;           // 0..10
    int o = blockIdx.y;            // 0..255
    int j = jb * 64 + lane;
    const float* mwr = merge_w + (size_t)o * KTOT;

    if (jb >= 3 && jb <= 6) {      // cols 192..447: pure copy
        if (wv == 0) Mw[(size_t)o * KTOT + j] = f2bf(mwr[j]);
        return;
    }
    float acc = 0.0f;
    if (jb == 0) {                 // K=64, slice 16/wave
        int k0 = wv * 16;
        #pragma unroll
        for (int k = 0; k < 16; ++k)
            acc += mwr[k0 + k] * lin2_w[(k0 + k) * 64 + lane];
    } else if (jb <= 2) {          // K=128, slice 32/wave
        int jj = (jb - 1) * 64 + lane;
        int k0 = wv * 32;
        #pragma unroll
        for (int k = 0; k < 32; ++k)
            acc += mwr[64 + k0 + k] * lin1_w[(k0 + k) * 128 + jj];
    } else {                       // jb 7..10: K=256, slice 64/wave
        int jj = (jb - 7) * 64 + lane;
        int k0 = wv * 64;
        #pragma unroll
        for (int k = 0; k < 64; ++k)
            acc += mwr[448 + k0 + k] * lin0_w[(k0 + k) * 256 + jj];
    }
    red[wv][lane] = acc;
    __syncthreads();
    if (wv == 0) {
        float t = red[0][lane] + red[1][lane] + red[2][lane] + red[3][lane];
        Mw[(size_t)o * KTOT + j] = f2bf(t);
    }
}

// ===== fuse_bias: biasf[256] via wave-per-row shuffle reduce; zeroes cnt =====
__global__ __launch_bounds__(256) void fuse_bias(const float* __restrict__ merge_w,
                                                 const float* __restrict__ merge_b,
                                                 const float* __restrict__ lin0_b,
                                                 const float* __restrict__ lin1_b,
                                                 const float* __restrict__ lin2_b,
                                                 float* __restrict__ biasf,
                                                 int* __restrict__ cnt) {
    int lane = threadIdx.x & 63;
    int wv = threadIdx.x >> 6;
    int o = blockIdx.x * 4 + wv;
    if (blockIdx.x == 0 && threadIdx.x < 4) cnt[threadIdx.x * 64] = 0;
    const float* mwr = merge_w + (size_t)o * KTOT;
    float acc = 0.0f;
    #pragma unroll
    for (int i = 0; i < 11; ++i) {
        int k = i * 64 + lane;
        float c;
        if (k < 64) c = lin2_b[k];
        else if (k < 192) c = lin1_b[k - 64];
        else if (k < 448) c = 0.0f;
        else c = lin0_b[k - 448];
        acc += mwr[k] * c;
    }
    #pragma unroll
    for (int off = 32; off > 0; off >>= 1) acc += __shfl_xor(acc, off, 64);
    if (lane == 0) biasf[o] = merge_b[o] + acc;
}

// ===== transpose_d4: d4 [B][256][30][40] -> d4T [B][1200][256] (bf16) =====
__global__ __launch_bounds__(256) void transpose_d4(const float* __restrict__ d4,
                                                    short* __restrict__ d4T) {
    __shared__ float T[64][65];
    int b = blockIdx.z;
    int p0 = blockIdx.x * 64;   // pixel tile (19 tiles over 1200)
    int c0 = blockIdx.y * 64;   // channel tile (4 tiles over 256)
    for (int t = threadIdx.x; t < 4096; t += 256) {
        int ch = t >> 6, px = t & 63;            // px fast -> coalesced read
        int gp = p0 + px;
        if (gp < 1200)
            T[ch][px] = d4[((size_t)(b * 256 + c0 + ch)) * 1200 + gp];
    }
    __syncthreads();
    for (int t = threadIdx.x; t < 4096; t += 256) {
        int px = t >> 6, ch = t & 63;            // ch fast -> coalesced write
        int gp = p0 + px;
        if (gp < 1200)
            d4T[((size_t)(b * 1200 + gp)) * 256 + c0 + ch] = f2bf(T[ch][px]);
    }
}

// ===== transpose_cDa: cDa [B][256][60][80] -> cDaT [B][4800][256] (bf16) =====
__global__ __launch_bounds__(256) void transpose_cDa(const float* __restrict__ cDa,
                                                     short* __restrict__ cDaT) {
    __shared__ float T[64][65];
    int b = blockIdx.z;
    int p0 = blockIdx.x * 64;   // pixel tile (75 tiles over 4800, exact)
    int c0 = blockIdx.y * 64;   // channel tile (4 tiles over 256)
    for (int t = threadIdx.x; t < 4096; t += 256) {
        int ch = t >> 6, px = t & 63;            // px fast -> coalesced read
        T[ch][px] = cDa[((size_t)(b * 256 + c0 + ch)) * 4800 + p0 + px];
    }
    __syncthreads();
    for (int t = threadIdx.x; t < 4096; t += 256) {
        int px = t >> 6, ch = t & 63;            // ch fast -> coalesced write
        cDaT[((size_t)(b * 4800 + p0 + px)) * 256 + c0 + ch] = f2bf(T[ch][px]);
    }
}

// ===== transpose_d2: d2 [B][128][120][160] -> d2T [B][19200][128] (bf16) =====
__global__ __launch_bounds__(256) void transpose_d2(const float* __restrict__ d2,
                                                    short* __restrict__ d2T) {
    __shared__ float T[64][65];
    int b = blockIdx.z;
    int p0 = blockIdx.x * 64;   // pixel tile (300 tiles over 19200, exact)
    int c0 = blockIdx.y * 64;   // channel tile (2 tiles over 128)
    for (int t = threadIdx.x; t < 4096; t += 256) {
        int ch = t >> 6, px = t & 63;            // px fast -> coalesced read
        T[ch][px] = d2[((size_t)(b * 128 + c0 + ch)) * 19200 + p0 + px];
    }
    __syncthreads();
    for (int t = threadIdx.x; t < 4096; t += 256) {
        int px = t >> 6, ch = t & 63;            // ch fast -> coalesced write
        d2T[((size_t)(b * 19200 + p0 + px)) * 128 + c0 + ch] = f2bf(T[ch][px]);
    }
}

// ===== nms_fused: mask0 in-LDS + 4 pools + compaction (proven 512-thread form) =====
__global__ __launch_bounds__(512) void nms_fused(const float* __restrict__ scores,
                                                 unsigned long long* __restrict__ cand,
                                                 int* __restrict__ cnt) {
    __shared__ float S72[72 * 72];
    __shared__ float T72[72 * 64];
    __shared__ float Mm[64 * 64];
    __shared__ float Zm[56 * 56];
    __shared__ int lcnt, gbase;
    int bz = blockIdx.z;
    int x0 = blockIdx.x * 32, y0 = blockIdx.y * 32;
    const float* sp = scores + bz * HW;
    if (threadIdx.x == 0) lcnt = 0;
    for (int t = threadIdx.x; t < 5184; t += 512) {
        int i = t / 72, j = t - i * 72;
        int gy = y0 - 20 + i, gx = x0 - 20 + j;
        S72[t] = (gy >= 0 && gy < H && gx >= 0 && gx < W) ? sp[gy * W + gx] : -1.0f;
    }
    __syncthreads();
    for (int t = threadIdx.x; t < 4608; t += 512) {
        int i = t >> 6, c = t & 63;
        T72[i * 64 + c] = MAX9(S72, i * 72 + c, 1);
    }
    __syncthreads();
    for (int t = threadIdx.x; t < 4096; t += 512) {
        int r = t >> 6, c = t & 63;
        float m = MAX9(T72, r * 64 + c, 64);
        float s = S72[(r + 4) * 72 + c + 4];
        int gy = y0 - 16 + r, gx = x0 - 16 + c;
        Mm[t] = (gy >= 0 && gy < H && gx >= 0 && gx < W && s == m) ? 1.0f : 0.0f;
    }
    __syncthreads();
    float* Tm = T72;
    for (int t = threadIdx.x; t < 3584; t += 512) {
        int i = t / 56, c = t - i * 56;
        Tm[i * 56 + c] = MAX9(Mm, i * 64 + c, 1);
    }
    __syncthreads();
    for (int t = threadIdx.x; t < 3136; t += 512) {
        int i = t / 56, j = t - i * 56;
        float m = MAX9(Tm, i * 56 + j, 56);
        Zm[t] = (m > 0.0f) ? -1.0f : S72[(i + 8) * 72 + (j + 8)];
    }
    __syncthreads();
    for (int t = threadIdx.x; t < 2688; t += 512) {
        int i = t / 48, c = t - i * 48;
        Tm[i * 56 + c] = MAX9(Zm, i * 56 + c, 1);
    }
    __syncthreads();
    for (int t = threadIdx.x; t < 2304; t += 512) {
        int r = t / 48, c = t - r * 48;
        float m = MAX9(Tm, r * 56 + c, 56);
        float Zc = Zm[(r + 4) * 56 + c + 4];
        int mi = (r + 8) * 64 + c + 8;
        bool nm = (Zc == m) && (Zc >= 0.0f);
        Mm[mi] = (Mm[mi] != 0.0f || nm) ? 1.0f : 0.0f;
    }
    __syncthreads();
    for (int t = threadIdx.x; t < 1920; t += 512) {
        int r = t / 40, c = t - r * 40;
        Tm[r * 56 + c] = MAX9(Mm, (r + 8) * 64 + c + 8, 1);
    }
    __syncthreads();
    for (int t = threadIdx.x; t < 1600; t += 512) {
        int r = t / 40, c = t - r * 40;
        float m = MAX9(Tm, r * 56 + c, 56);
        int zi = (r + 8) * 56 + c + 8;
        Zm[zi] = (m > 0.0f) ? -1.0f : S72[(r + 16) * 72 + (c + 16)];
    }
    __syncthreads();
    for (int t = threadIdx.x; t < 1280; t += 512) {
        int r = t / 32, c = t & 31;
        Tm[r * 56 + c] = MAX9(Zm, (r + 8) * 56 + c + 8, 1);
    }
    __syncthreads();
    unsigned long long keys[2];
    int nl = 0;
    #pragma unroll
    for (int q = 0; q < 2; ++q) {
        int t = threadIdx.x + q * 512;
        int r3 = t >> 5, c = t & 31;
        float m = MAX9(Tm, r3 * 56 + c, 56);
        float Zc = Zm[(r3 + 12) * 56 + c + 12];
        bool fin = (Mm[(r3 + 16) * 64 + c + 16] != 0.0f) || ((Zc == m) && (Zc >= 0.0f));
        int gy = y0 + r3, gx = x0 + c;
        float sc = S72[(r3 + 20) * 72 + (c + 20)];
        if (fin && gy >= 4 && gy < H - 4 && gx >= 4 && gx < W - 4 && sc > THRESH) {
            unsigned r = (unsigned)(gy * W + gx);
            unsigned bits = __float_as_uint(sc) | 0x80000000u;
            keys[nl++] = ((unsigned long long)bits << 32) |
                         (unsigned long long)(0xFFFFFFFFu - r);
        }
    }
    int lpos = 0;
    if (nl) lpos = atomicAdd(&lcnt, nl);
    __syncthreads();
    if (threadIdx.x == 0) gbase = (lcnt > 0) ? atomicAdd(&cnt[bz * 64], lcnt) : 0;
    __syncthreads();
    for (int j = 0; j < nl; ++j) {
        int p = gbase + lpos + j;
        if (p < CAP) cand[(size_t)bz * CAP + p] = keys[j];
    }
}

// ===== topk: histogram select + LOW-BARRIER scans + hybrid shuffle bitonic =====
__global__ __launch_bounds__(1024) void topk(const unsigned long long* __restrict__ cand,
                                             const int* __restrict__ cnt,
                                             float* __restrict__ out, int* __restrict__ fidx,
                                             int* __restrict__ perm) {
    __shared__ int hist[2048];
    __shared__ int wtot[16], wcarry[16];
    __shared__ unsigned long long buf[4096];
    __shared__ int scnt, spiv1, spiv2, sabove;
    int b = blockIdx.x, tid = threadIdx.x;
    int lane = tid & 63, wv = tid >> 6;    // 16 waves
    int m = cnt[b * 64]; if (m > CAP) m = CAP;
    const unsigned long long* cb = cand + (size_t)b * CAP;
    int target = (m < 1024) ? m : 1024;

    hist[tid] = 0; hist[tid + 1024] = 0;
    if (tid == 0) { scnt = 0; spiv1 = 2048; spiv2 = 0; sabove = 0; }
    __syncthreads();
    for (int i = tid; i < m; i += 1024)
        atomicAdd(&hist[(int)(cb[i] >> 53) & 0x7FF], 1);
    __syncthreads();
    // ---- inclusive suffix sum over hist[0..2047], wave-hierarchical ----
    {
        int base = wv * 128;
        int a = hist[base + lane];
        int c = hist[base + 64 + lane];
        int as = a, cs = c;
        #pragma unroll
        for (int off = 1; off < 64; off <<= 1) {
            int t1 = __shfl_down(as, off, 64);
            if (lane + off < 64) as += t1;
            int t2 = __shfl_down(cs, off, 64);
            if (lane + off < 64) cs += t2;
        }
        int ctot = __shfl(cs, 0, 64);
        as += ctot;
        if (lane == 0) wtot[wv] = as;
        __syncthreads();
        if (wv == 0 && lane < 16) {
            int v = wtot[lane];
            #pragma unroll
            for (int off = 1; off < 16; off <<= 1) {
                int t1 = __shfl_down(v, off, 64);
                if (lane + off < 16) v += t1;
            }
            wcarry[lane] = v - wtot[lane];
        }
        __syncthreads();
        int carry = wcarry[wv];
        hist[base + lane] = as + carry;
        hist[base + 64 + lane] = cs + carry;
    }
    __syncthreads();
    if (target > 0) {
        for (int t = tid; t < 2048; t += 1024) {
            int c = hist[t];
            int cn = (t < 2047) ? hist[t + 1] : 0;
            if (c >= target && cn < target) { spiv1 = t; sabove = cn; }
        }
    }
    __syncthreads();
    int piv1 = spiv1;
    int target2 = target - sabove;
    hist[tid] = 0; hist[tid + 1024] = 0;
    __syncthreads();
    for (int i = tid; i < m; i += 1024) {
        unsigned long long k = cb[i];
        if (((int)(k >> 53) & 0x7FF) == piv1)
            atomicAdd(&hist[(int)(k >> 42) & 0x7FF], 1);
    }
    __syncthreads();
    {
        int base = wv * 128;
        int a = hist[base + lane];
        int c = hist[base + 64 + lane];
        int as = a, cs = c;
        #pragma unroll
        for (int off = 1; off < 64; off <<= 1) {
            int t1 = __shfl_down(as, off, 64);
            if (lane + off < 64) as += t1;
            int t2 = __shfl_down(cs, off, 64);
            if (lane + off < 64) cs += t2;
        }
        int ctot = __shfl(cs, 0, 64);
        as += ctot;
        if (lane == 0) wtot[wv] = as;
        __syncthreads();
        if (wv == 0 && lane < 16) {
            int v = wtot[lane];
            #pragma unroll
            for (int off = 1; off < 16; off <<= 1) {
                int t1 = __shfl_down(v, off, 64);
                if (lane + off < 16) v += t1;
            }
            wcarry[lane] = v - wtot[lane];
        }
        __syncthreads();
        int carry = wcarry[wv];
        hist[base + lane] = as + carry;
        hist[base + 64 + lane] = cs + carry;
    }
    __syncthreads();
    if (target > 0) {
        for (int t = tid; t < 2048; t += 1024) {
            int c = hist[t];
            int cn = (t < 2047) ? hist[t + 1] : 0;
            if (c >= target2 && cn < target2) spiv2 = t;
        }
    }
    __syncthreads();
    int piv2 = spiv2;
    for (int i = tid; i < m; i += 1024) {
        unsigned long long k = cb[i];
        int b1 = (int)(k >> 53) & 0x7FF;
        bool sel = (target > 0) &&
                   (b1 > piv1 || (b1 == piv1 && (((int)(k >> 42) & 0x7FF) >= piv2)));
        if (sel) {
            int p = atomicAdd(&scnt, 1);
            if (p < 4096) buf[p] = k;
        }
    }
    __syncthreads();
    int sc_ = scnt; if (sc_ > 4096) sc_ = 4096;
    int ns = 1024; while (ns < sc_) ns <<= 1;
    for (int t = tid; t < ns; t += 1024) if (t >= sc_) buf[t] = 0ULL;
    __syncthreads();
    // ---- hybrid bitonic sort, descending ----
    int nseg = ns >> 6;
    for (int seg = wv; seg < nseg; seg += 16) {
        int e = (seg << 6) + lane;
        unsigned long long v = buf[e];
        #pragma unroll
        for (int k = 2; k <= 64; k <<= 1) {
            #pragma unroll
            for (int j = k >> 1; j >= 1; j >>= 1) {
                unsigned long long p = __shfl_xor(v, j, 64);
                bool upper = (lane & j) != 0;
                bool dird = ((e & k) == 0);
                bool keepmax = (dird != upper);
                v = keepmax ? (v > p ? v : p) : (v < p ? v : p);
            }
        }
        buf[e] = v;
    }
    for (int k = 128; k <= ns; k <<= 1) {
        for (int j = k >> 1; j >= 64; j >>= 1) {
            __syncthreads();
            for (int t = tid; t < ns; t += 1024) {
                int ixj = t ^ j;
                if (ixj > t) {
                    unsigned long long a = buf[t], bb = buf[ixj];
                    if (((t & k) == 0) ? (a < bb) : (a > bb)) { buf[t] = bb; buf[ixj] = a; }
                }
            }
        }
        __syncthreads();
        for (int seg = wv; seg < nseg; seg += 16) {
            int e = (seg << 6) + lane;
            unsigned long long v = buf[e];
            #pragma unroll
            for (int j = 32; j >= 1; j >>= 1) {
                unsigned long long p = __shfl_xor(v, j, 64);
                bool upper = (lane & j) != 0;
                bool dird = ((e & k) == 0);
                bool keepmax = (dird != upper);
                v = keepmax ? (v > p ? v : p) : (v < p ? v : p);
            }
            buf[e] = v;
        }
    }
    __syncthreads();
    unsigned long long key = buf[tid];
    float kx, ky, sc;
    unsigned idx;
    if (key != 0ULL) {
        unsigned ord = (unsigned)(key >> 32);
        sc = __uint_as_float(ord ^ 0x80000000u);
        idx = 0xFFFFFFFFu - (unsigned)(key & 0xFFFFFFFFu);
        kx = (float)(idx % W);
        ky = (float)(idx / W);
    } else {
        sc = -1.0f; idx = 0; kx = 0.0f; ky = 0.0f;
    }
    int bn = b * NKP + tid;
    out[bn * 2 + 0] = kx;
    out[bn * 2 + 1] = ky;
    out[B * NKP * 2 + bn] = sc;
    fidx[bn] = (int)idx;
    __syncthreads();
    // ---- spatial perm via counting sort; wave-hierarchical prefix ----
    if (tid < 512) { hist[tid] = 0; hist[tid + 1024] = 0; }
    __syncthreads();
    int bucket = (int)(idx >> 10);          // < 300
    atomicAdd(&hist[bucket], 1);
    __syncthreads();
    int iv = 0;
    if (wv < 8) {
        iv = hist[wv * 64 + lane];
        #pragma unroll
        for (int off = 1; off < 64; off <<= 1) {
            int t1 = __shfl_up(iv, off, 64);
            if (lane >= off) iv += t1;
        }
        if (lane == 63) wtot[wv] = iv;
    }
    __syncthreads();
    if (wv == 0 && lane < 8) {
        int v = wtot[lane], iv2 = v;
        #pragma unroll
        for (int off = 1; off < 8; off <<= 1) {
            int t1 = __shfl_up(iv2, off, 64);
            if (lane >= off) iv2 += t1;
        }
        wcarry[lane] = iv2 - v;
    }
    __syncthreads();
    if (wv < 8) hist[512 + wv * 64 + lane] = iv + wcarry[wv];
    __syncthreads();
    int intra = atomicAdd(&hist[1024 + bucket], 1);
    int pos = hist[512 + bucket] - hist[bucket] + intra;
    perm[b * NKP + pos] = tid;
}

// ===== sample_all: wave-per-keypoint; bf16 NHWC for seg1/2/3 when copies exist =====
__global__ __launch_bounds__(256) void sample_all(const float* __restrict__ d1,
                                                  const float* __restrict__ d2,
                                                  const float* __restrict__ cDa,
                                                  const short* __restrict__ d4T,
                                                  const short* __restrict__ cDaT,
                                                  const short* __restrict__ d2T,
                                                  const int* __restrict__ fidx,
                                                  const int* __restrict__ perm,
                                                  short* __restrict__ X) {
    int lane = threadIdx.x & 63;
    int wv = threadIdx.x >> 6;
    int seg = blockIdx.y;
    int bid = blockIdx.x;
    int swz = ((bid & 7) << 7) | (bid >> 3);
    int b = swz >> 8;                  // 256 chunks per batch
    int g0 = ((swz & 255) << 2) + wv;  // kp slot within batch

    const float* map; int h, w, s, C, base, nset;
    if (seg == 0)      { map = d1;  h = 240; w = 320; s = 2;  C = 64;  base = 0;   nset = 1; }
    else if (seg == 1) { map = d2;  h = 120; w = 160; s = 4;  C = 128; base = 64;  nset = 2; }
    else if (seg == 2) { map = cDa; h = 60;  w = 80;  s = 8;  C = 256; base = 192; nset = 4; }
    else               { map = d1;  h = 30;  w = 40;  s = 16; C = 256; base = 448; nset = 4; }

    int col = (b << 10) | perm[(b << 10) + g0];
    int idx = fidx[col];
    float kx = (float)(idx % W);
    float ky = (float)(idx / W);
    float kxs = kx - (float)s * 0.5f + 0.5f;
    float kys = ky - (float)s * 0.5f + 0.5f;
    float gx = kxs / (float)(w * s - 1) * 2.0f - 1.0f;
    float gy = kys / (float)(h * s - 1) * 2.0f - 1.0f;
    float x = (gx + 1.0f) * 0.5f * (float)(w - 1);
    float y = (gy + 1.0f) * 0.5f * (float)(h - 1);
    float x0f = floorf(x), y0f = floorf(y);
    int x0 = (int)x0f, y0 = (int)y0f;
    float wx1 = x - x0f, wy1 = y - y0f;
    float wx0 = 1.0f - wx1, wy0 = 1.0f - wy1;
    bool vx0 = (x0 >= 0) && (x0 < w);
    bool vx1 = (x0 + 1 >= 0) && (x0 + 1 < w);
    bool vy0 = (y0 >= 0) && (y0 < h);
    bool vy1 = (y0 + 1 >= 0) && (y0 + 1 < h);
    int xc0 = min(max(x0, 0), w - 1), xc1 = min(max(x0 + 1, 0), w - 1);
    int yc0 = min(max(y0, 0), h - 1), yc1 = min(max(y0 + 1, 0), h - 1);
    float w00 = (vx0 && vy0) ? wx0 * wy0 : 0.0f;
    float w01 = (vx1 && vy0) ? wx1 * wy0 : 0.0f;
    float w10 = (vx0 && vy1) ? wx0 * wy1 : 0.0f;
    float w11 = (vx1 && vy1) ? wx1 * wy1 : 0.0f;

    bool nhwc = (seg == 3) || (seg == 2 && cDaT != nullptr) || (seg == 1 && d2T != nullptr);
    float vals[4];
    float r = 0.0f;
    if (nhwc) {
        const short* pt; int wq, Cc;
        if (seg == 3)      { pt = d4T + ((size_t)b * 1200) * 256 + lane;  wq = 40;  Cc = 256; }
        else if (seg == 2) { pt = cDaT + ((size_t)b * 4800) * 256 + lane; wq = 80;  Cc = 256; }
        else               { pt = d2T + ((size_t)b * 19200) * 128 + lane; wq = 160; Cc = 128; }
        size_t o00 = (size_t)(yc0 * wq + xc0) * Cc;
        size_t o01 = (size_t)(yc0 * wq + xc1) * Cc;
        size_t o10 = (size_t)(yc1 * wq + xc0) * Cc;
        size_t o11 = (size_t)(yc1 * wq + xc1) * Cc;
        float q00[4], q01[4], q10[4], q11[4];
        #pragma unroll
        for (int j = 0; j < 4; ++j) {
            if (j < nset) {
                q00[j] = bf2f(pt[o00 + j * 64]); q01[j] = bf2f(pt[o01 + j * 64]);
                q10[j] = bf2f(pt[o10 + j * 64]); q11[j] = bf2f(pt[o11 + j * 64]);
            }
        }
        #pragma unroll
        for (int j = 0; j < 4; ++j) {
            if (j < nset) {
                vals[j] = q00[j] * w00 + q01[j] * w01 + q10[j] * w10 + q11[j] * w11;
                r += vals[j] * vals[j];
            }
        }
    } else {
        int xb = min(xc0, w - 2);
        float s0 = (xc0 == xb) ? 1.0f : 0.0f;
        float s1 = (xc1 == xb) ? 1.0f : 0.0f;
        float ax = w00 * s0 + w01 * s1;
        float ay = w00 * (1.0f - s0) + w01 * (1.0f - s1);
        float bx = w10 * s0 + w11 * s1;
        float by = w10 * (1.0f - s0) + w11 * (1.0f - s1);
        size_t hw = (size_t)(h * w);
        const float* pb = map + ((size_t)b * C + lane) * hw;
        size_t off0 = (size_t)yc0 * w + xb;
        size_t off1 = (size_t)yc1 * w + xb;
        size_t cstr = hw << 6;   // 64 channel-planes
        f2u q0[4], q1[4];
        #pragma unroll
        for (int j = 0; j < 4; ++j) {
            if (j < nset) {
                const float* p = pb + (size_t)j * cstr;
                q0[j] = *(const f2u*)(p + off0);
                q1[j] = *(const f2u*)(p + off1);
            }
        }
        #pragma unroll
        for (int j = 0; j < 4; ++j) {
            if (j < nset) {
                vals[j] = q0[j].x * ax + q0[j].y * ay + q1[j].x * bx + q1[j].y * by;
                r += vals[j] * vals[j];
            }
        }
    }
    #pragma unroll
    for (int off = 32; off > 0; off >>= 1) r += __shfl_xor(r, off, 64);
    float denom = fmaxf(sqrtf(r), 1e-12f);
    float inv = 1.0f / denom;
    short* xp = X + (size_t)col * KTOT + base + lane;
    #pragma unroll
    for (int j = 0; j < 4; ++j) {
        if (j < nset) xp[j * 64] = f2bf(vals[j] * inv);
    }
}

// ===== GEMM (bf16 MFMA): out[256,4096] = Mw[256,704] * X^T + bias; bf16 inputs =====
__global__ __launch_bounds__(256) void gemm_mfma(const short* __restrict__ Mw,
                                                 const short* __restrict__ X,
                                                 const float* __restrict__ biasf,
                                                 float* __restrict__ out) {
    __shared__ short As[64 * 72];
    __shared__ short Bs[64 * 72];
    int tid = threadIdx.x;
    int lane = tid & 63, w = tid >> 6;
    int r = lane & 15, quad = lane >> 4;
    int rowBase = blockIdx.y * 64, colBase = blockIdx.x * 64;
    int sm = tid >> 2, skq = (tid & 3) << 4;   // 16 shorts (32B) per thread per tile

    const short* pa = Mw + (size_t)(rowBase + sm) * KTOT + skq;
    const short* pb = X + (size_t)(colBase + sm) * KTOT + skq;
    s8v a0 = *(const s8v*)(pa), a1 = *(const s8v*)(pa + 8);
    s8v b0 = *(const s8v*)(pb), b1 = *(const s8v*)(pb + 8);

    f4v acc[4];
    #pragma unroll
    for (int t = 0; t < 4; ++t) acc[t] = (f4v)0.0f;

    for (int kt = 0; kt < 11; ++kt) {
        __syncthreads();
        *(s8v*)&As[sm * 72 + skq + 0] = a0;
        *(s8v*)&As[sm * 72 + skq + 8] = a1;
        *(s8v*)&Bs[sm * 72 + skq + 0] = b0;
        *(s8v*)&Bs[sm * 72 + skq + 8] = b1;
        __syncthreads();
        if (kt < 10) {
            pa += 64; pb += 64;
            a0 = *(const s8v*)(pa); a1 = *(const s8v*)(pa + 8);
            b0 = *(const s8v*)(pb); b1 = *(const s8v*)(pb + 8);
        }
        #pragma unroll
        for (int kk = 0; kk < 2; ++kk) {
            int aoff = (w * 16 + r) * 72 + kk * 32 + quad * 8;
            s8v af = *(const s8v*)&As[aoff];
            #pragma unroll
            for (int t = 0; t < 4; ++t) {
                int boff = (t * 16 + r) * 72 + kk * 32 + quad * 8;
                s8v bf = *(const s8v*)&Bs[boff];
                acc[t] = __builtin_amdgcn_mfma_f32_16x16x32_bf16(af, bf, acc[t], 0, 0, 0);
            }
        }
    }
    #pragma unroll
    for (int t = 0; t < 4; ++t) {
        int colg = colBase + t * 16 + r;
        size_t obase = (size_t)(colg >> 10) * (256 * NKP) + (size_t)(colg & 1023);
        #pragma unroll
        for (int reg = 0; reg < 4; ++reg) {
            int row = rowBase + w * 16 + quad * 4 + reg;
            out[obase + (size_t)row * NKP] = acc[t][reg] + biasf[row];
        }
    }
}

// ================= launch =================
extern "C" void kernel_launch(void* const* d_in, const int* in_sizes, int n_in,
                              void* d_out, int out_size, void* d_ws, size_t ws_size,
                              hipStream_t stream) {
    const float* scores  = (const float*)d_in[0];
    const float* d1      = (const float*)d_in[1];
    const float* d2      = (const float*)d_in[2];
    const float* cDa     = (const float*)d_in[3];
    const float* d4      = (const float*)d_in[4];
    const float* lin0_w  = (const float*)d_in[5];
    const float* lin0_b  = (const float*)d_in[6];
    const float* lin1_w  = (const float*)d_in[7];
    const float* lin1_b  = (const float*)d_in[8];
    const float* lin2_w  = (const float*)d_in[9];
    const float* lin2_b  = (const float*)d_in[10];
    const float* merge_w = (const float*)d_in[11];
    const float* merge_b = (const float*)d_in[12];
    float* out = (float*)d_out;

    char* ws = (char*)d_ws;
    short* Xbuf = (short*)ws;                                          // 5.77 MB
    short* d4T  = (short*)(ws + 6291456);                              // 2,457,600 B (bf16)
    unsigned long long* cand  = (unsigned long long*)(ws + 14745600);  // 524,288 B
    int* cnt                  = (int*)(ws + 15269888);                 // 1,024 B
    int* fidx                 = (int*)(ws + 15401984);                 // 16,384 B
    short* Mw                 = (short*)(ws + 15418368);               // 360,448 B (bf16)
    float* biasf              = (float*)(ws + 16139264);               // 1,024 B
    int* perm                 = (int*)(ws + 16140288);                 // 16,384 B
    // bf16 transposed copies past the legacy 16.16 MB layout, when ws allows
    // (conditions use the conservative f32-era thresholds, known to hold).
    short* cDaT = nullptr;   // 9,830,400 B at +16,156,672
    short* d2T  = nullptr;   // 19,660,800 B at +35,817,472
    if (ws_size >= 16156672ULL + 19660800ULL)
        cDaT = (short*)(ws + 16156672);
    if (ws_size >= 35817472ULL + 39321600ULL)
        d2T = (short*)(ws + 35817472);

    dim3 tgrid(W / 32, H / 32, B);   // (20,15,4)

    fuse_w<<<dim3(11, 256), 256, 0, stream>>>(merge_w, lin0_w, lin1_w, lin2_w, Mw);
    fuse_bias<<<64, 256, 0, stream>>>(merge_w, merge_b, lin0_b, lin1_b, lin2_b, biasf, cnt);
    transpose_d4<<<dim3(19, 4, 4), 256, 0, stream>>>(d4, d4T);
    if (cDaT)
        transpose_cDa<<<dim3(75, 4, 4), 256, 0, stream>>>(cDa, cDaT);
    if (d2T)
        transpose_d2<<<dim3(300, 2, 4), 256, 0, stream>>>(d2, d2T);
    nms_fused<<<tgrid, 512, 0, stream>>>(scores, cand, cnt);
    topk<<<B, 1024, 0, stream>>>(cand, cnt, out, fidx, perm);
    sample_all<<<dim3(1024, 4), 256, 0, stream>>>(d1, d2, cDa, d4T, cDaT, d2T,
                                                  fidx, perm, Xbuf);
    gemm_mfma<<<dim3(NCOL / 64, 256 / 64), 256, 0, stream>>>(Mw, Xbuf, biasf, out + B * NKP * 3);
}

// Round 15
// 296.866 us; speedup vs baseline: 1.0220x; 1.0220x over previous
//
#include <hip/hip_runtime.h>
#include <hip/hip_bf16.h>

#define B 4
#define H 480
#define W 640
#define HW (H*W)
#define BHW (B*H*W)
#define NKP 1024
#define THRESH 0.005f
#define CAP 16384
#define NCOL (B*NKP)
#define KTOT 704

typedef __attribute__((ext_vector_type(8))) short s8v;
typedef __attribute__((ext_vector_type(4))) float f4v;
typedef struct { float x, y; } __attribute__((aligned(4))) f2u;   // 4B-aligned pair load

__device__ __forceinline__ short f2bf(float f) {
    __hip_bfloat16 h = __float2bfloat16(f);
    return *(short*)&h;
}

__device__ __forceinline__ float max3f(float a, float b, float c) {
    return fmaxf(fmaxf(a, b), c);     // clang fuses to v_max3_f32
}
// 9-wide max as a depth-2 tree of v_max3_f32 (4 instrs vs 8-deep chain)
#define MAX9(A, base, str) \
    max3f(max3f((A)[(base)], (A)[(base)+(str)], (A)[(base)+2*(str)]), \
          max3f((A)[(base)+3*(str)], (A)[(base)+4*(str)], (A)[(base)+5*(str)]), \
          max3f((A)[(base)+6*(str)], (A)[(base)+7*(str)], (A)[(base)+8*(str)]))

// ===== fuse_w: Mw[256,704] weight fold; block=(64 cols x 4 K-slice waves) =====
__global__ __launch_bounds__(256) void fuse_w(const float* __restrict__ merge_w,
                                              const float* __restrict__ lin0_w,
                                              const float* __restrict__ lin1_w,
                                              const float* __restrict__ lin2_w,
                                              short* __restrict__ Mw) {
    __shared__ float red[4][64];
    int lane = threadIdx.x & 63;
    int wv = threadIdx.x >> 6;
    int jb = blockIdx.x;           // 0..10
    int o = blockIdx.y;            // 0..255
    int j = jb * 64 + lane;
    const float* mwr = merge_w + (size_t)o * KTOT;

    if (jb >= 3 && jb <= 6) {      // cols 192..447: pure copy
        if (wv == 0) Mw[(size_t)o * KTOT + j] = f2bf(mwr[j]);
        return;
    }
    float acc = 0.0f;
    if (jb == 0) {                 // K=64, slice 16/wave
        int k0 = wv * 16;
        #pragma unroll
        for (int k = 0; k < 16; ++k)
            acc += mwr[k0 + k] * lin2_w[(k0 + k) * 64 + lane];
    } else if (jb <= 2) {          // K=128, slice 32/wave
        int jj = (jb - 1) * 64 + lane;
        int k0 = wv * 32;
        #pragma unroll
        for (int k = 0; k < 32; ++k)
            acc += mwr[64 + k0 + k] * lin1_w[(k0 + k) * 128 + jj];
    } else {                       // jb 7..10: K=256, slice 64/wave
        int jj = (jb - 7) * 64 + lane;
        int k0 = wv * 64;
        #pragma unroll
        for (int k = 0; k < 64; ++k)
            acc += mwr[448 + k0 + k] * lin0_w[(k0 + k) * 256 + jj];
    }
    red[wv][lane] = acc;
    __syncthreads();
    if (wv == 0) {
        float t = red[0][lane] + red[1][lane] + red[2][lane] + red[3][lane];
        Mw[(size_t)o * KTOT + j] = f2bf(t);
    }
}

// ===== fuse_bias: biasf[256] via wave-per-row shuffle reduce; zeroes cnt =====
__global__ __launch_bounds__(256) void fuse_bias(const float* __restrict__ merge_w,
                                                 const float* __restrict__ merge_b,
                                                 const float* __restrict__ lin0_b,
                                                 const float* __restrict__ lin1_b,
                                                 const float* __restrict__ lin2_b,
                                                 float* __restrict__ biasf,
                                                 int* __restrict__ cnt) {
    int lane = threadIdx.x & 63;
    int wv = threadIdx.x >> 6;
    int o = blockIdx.x * 4 + wv;
    if (blockIdx.x == 0 && threadIdx.x < 4) cnt[threadIdx.x * 64] = 0;
    const float* mwr = merge_w + (size_t)o * KTOT;
    float acc = 0.0f;
    #pragma unroll
    for (int i = 0; i < 11; ++i) {
        int k = i * 64 + lane;
        float c;
        if (k < 64) c = lin2_b[k];
        else if (k < 192) c = lin1_b[k - 64];
        else if (k < 448) c = 0.0f;
        else c = lin0_b[k - 448];
        acc += mwr[k] * c;
    }
    #pragma unroll
    for (int off = 32; off > 0; off >>= 1) acc += __shfl_xor(acc, off, 64);
    if (lane == 0) biasf[o] = merge_b[o] + acc;
}

// ===== transpose_d4: d4 [B][256][30][40] -> d4T [B][1200][256] (f32, exact) =====
__global__ __launch_bounds__(256) void transpose_d4(const float* __restrict__ d4,
                                                    float* __restrict__ d4T) {
    __shared__ float T[64][65];
    int b = blockIdx.z;
    int p0 = blockIdx.x * 64;   // pixel tile (19 tiles over 1200)
    int c0 = blockIdx.y * 64;   // channel tile (4 tiles over 256)
    for (int t = threadIdx.x; t < 4096; t += 256) {
        int ch = t >> 6, px = t & 63;            // px fast -> coalesced read
        int gp = p0 + px;
        if (gp < 1200)
            T[ch][px] = d4[((size_t)(b * 256 + c0 + ch)) * 1200 + gp];
    }
    __syncthreads();
    for (int t = threadIdx.x; t < 4096; t += 256) {
        int px = t >> 6, ch = t & 63;            // ch fast -> coalesced write
        int gp = p0 + px;
        if (gp < 1200)
            d4T[((size_t)(b * 1200 + gp)) * 256 + c0 + ch] = T[ch][px];
    }
}

// ===== transpose_cDa: cDa [B][256][60][80] -> cDaT [B][4800][256] (f32, exact) =====
__global__ __launch_bounds__(256) void transpose_cDa(const float* __restrict__ cDa,
                                                     float* __restrict__ cDaT) {
    __shared__ float T[64][65];
    int b = blockIdx.z;
    int p0 = blockIdx.x * 64;   // pixel tile (75 tiles over 4800, exact)
    int c0 = blockIdx.y * 64;   // channel tile (4 tiles over 256)
    for (int t = threadIdx.x; t < 4096; t += 256) {
        int ch = t >> 6, px = t & 63;            // px fast -> coalesced read
        T[ch][px] = cDa[((size_t)(b * 256 + c0 + ch)) * 4800 + p0 + px];
    }
    __syncthreads();
    for (int t = threadIdx.x; t < 4096; t += 256) {
        int px = t >> 6, ch = t & 63;            // ch fast -> coalesced write
        cDaT[((size_t)(b * 4800 + p0 + px)) * 256 + c0 + ch] = T[ch][px];
    }
}

// ===== nms_fused: mask0 recomputed in-LDS + 4 pools + compaction =====
__global__ __launch_bounds__(512) void nms_fused(const float* __restrict__ scores,
                                                 unsigned long long* __restrict__ cand,
                                                 int* __restrict__ cnt) {
    __shared__ float S72[72 * 72];
    __shared__ float T72[72 * 64];
    __shared__ float Mm[64 * 64];
    __shared__ float Zm[56 * 56];
    __shared__ int lcnt, gbase;
    int bz = blockIdx.z;
    int x0 = blockIdx.x * 32, y0 = blockIdx.y * 32;
    const float* sp = scores + bz * HW;
    if (threadIdx.x == 0) lcnt = 0;
    for (int t = threadIdx.x; t < 5184; t += 512) {
        int i = t / 72, j = t - i * 72;
        int gy = y0 - 20 + i, gx = x0 - 20 + j;
        S72[t] = (gy >= 0 && gy < H && gx >= 0 && gx < W) ? sp[gy * W + gx] : -1.0f;
    }
    __syncthreads();
    for (int t = threadIdx.x; t < 4608; t += 512) {
        int i = t >> 6, c = t & 63;
        T72[i * 64 + c] = MAX9(S72, i * 72 + c, 1);
    }
    __syncthreads();
    for (int t = threadIdx.x; t < 4096; t += 512) {
        int r = t >> 6, c = t & 63;
        float m = MAX9(T72, r * 64 + c, 64);
        float s = S72[(r + 4) * 72 + c + 4];
        int gy = y0 - 16 + r, gx = x0 - 16 + c;
        Mm[t] = (gy >= 0 && gy < H && gx >= 0 && gx < W && s == m) ? 1.0f : 0.0f;
    }
    __syncthreads();
    float* Tm = T72;
    for (int t = threadIdx.x; t < 3584; t += 512) {
        int i = t / 56, c = t - i * 56;
        Tm[i * 56 + c] = MAX9(Mm, i * 64 + c, 1);
    }
    __syncthreads();
    for (int t = threadIdx.x; t < 3136; t += 512) {
        int i = t / 56, j = t - i * 56;
        float m = MAX9(Tm, i * 56 + j, 56);
        Zm[t] = (m > 0.0f) ? -1.0f : S72[(i + 8) * 72 + (j + 8)];
    }
    __syncthreads();
    for (int t = threadIdx.x; t < 2688; t += 512) {
        int i = t / 48, c = t - i * 48;
        Tm[i * 56 + c] = MAX9(Zm, i * 56 + c, 1);
    }
    __syncthreads();
    for (int t = threadIdx.x; t < 2304; t += 512) {
        int r = t / 48, c = t - r * 48;
        float m = MAX9(Tm, r * 56 + c, 56);
        float Zc = Zm[(r + 4) * 56 + c + 4];
        int mi = (r + 8) * 64 + c + 8;
        bool nm = (Zc == m) && (Zc >= 0.0f);
        Mm[mi] = (Mm[mi] != 0.0f || nm) ? 1.0f : 0.0f;
    }
    __syncthreads();
    for (int t = threadIdx.x; t < 1920; t += 512) {
        int r = t / 40, c = t - r * 40;
        Tm[r * 56 + c] = MAX9(Mm, (r + 8) * 64 + c + 8, 1);
    }
    __syncthreads();
    for (int t = threadIdx.x; t < 1600; t += 512) {
        int r = t / 40, c = t - r * 40;
        float m = MAX9(Tm, r * 56 + c, 56);
        int zi = (r + 8) * 56 + c + 8;
        Zm[zi] = (m > 0.0f) ? -1.0f : S72[(r + 16) * 72 + (c + 16)];
    }
    __syncthreads();
    for (int t = threadIdx.x; t < 1280; t += 512) {
        int r = t / 32, c = t & 31;
        Tm[r * 56 + c] = MAX9(Zm, (r + 8) * 56 + c + 8, 1);
    }
    __syncthreads();
    unsigned long long keys[2];
    int nl = 0;
    #pragma unroll
    for (int q = 0; q < 2; ++q) {
        int t = threadIdx.x + q * 512;
        int r3 = t >> 5, c = t & 31;
        float m = MAX9(Tm, r3 * 56 + c, 56);
        float Zc = Zm[(r3 + 12) * 56 + c + 12];
        bool fin = (Mm[(r3 + 16) * 64 + c + 16] != 0.0f) || ((Zc == m) && (Zc >= 0.0f));
        int gy = y0 + r3, gx = x0 + c;
        float sc = S72[(r3 + 20) * 72 + (c + 20)];
        if (fin && gy >= 4 && gy < H - 4 && gx >= 4 && gx < W - 4 && sc > THRESH) {
            unsigned r = (unsigned)(gy * W + gx);
            unsigned bits = __float_as_uint(sc) | 0x80000000u;
            keys[nl++] = ((unsigned long long)bits << 32) |
                         (unsigned long long)(0xFFFFFFFFu - r);
        }
    }
    int lpos = 0;
    if (nl) lpos = atomicAdd(&lcnt, nl);
    __syncthreads();
    if (threadIdx.x == 0) gbase = (lcnt > 0) ? atomicAdd(&cnt[bz * 64], lcnt) : 0;
    __syncthreads();
    for (int j = 0; j < nl; ++j) {
        int p = gbase + lpos + j;
        if (p < CAP) cand[(size_t)bz * CAP + p] = keys[j];
    }
}

// ===== topk: histogram select + LOW-BARRIER scans + hybrid shuffle bitonic =====
__global__ __launch_bounds__(1024) void topk(const unsigned long long* __restrict__ cand,
                                             const int* __restrict__ cnt,
                                             float* __restrict__ out, int* __restrict__ fidx,
                                             int* __restrict__ perm) {
    __shared__ int hist[2048];
    __shared__ int wtot[16], wcarry[16];
    __shared__ unsigned long long buf[4096];
    __shared__ int scnt, spiv1, spiv2, sabove;
    int b = blockIdx.x, tid = threadIdx.x;
    int lane = tid & 63, wv = tid >> 6;    // 16 waves
    int m = cnt[b * 64]; if (m > CAP) m = CAP;
    const unsigned long long* cb = cand + (size_t)b * CAP;
    int target = (m < 1024) ? m : 1024;

    hist[tid] = 0; hist[tid + 1024] = 0;
    if (tid == 0) { scnt = 0; spiv1 = 2048; spiv2 = 0; sabove = 0; }
    __syncthreads();
    for (int i = tid; i < m; i += 1024)
        atomicAdd(&hist[(int)(cb[i] >> 53) & 0x7FF], 1);
    __syncthreads();
    // ---- inclusive suffix sum over hist[0..2047], wave-hierarchical (3 barriers) ----
    {
        int base = wv * 128;
        int a = hist[base + lane];
        int c = hist[base + 64 + lane];
        int as = a, cs = c;
        #pragma unroll
        for (int off = 1; off < 64; off <<= 1) {
            int t1 = __shfl_down(as, off, 64);
            if (lane + off < 64) as += t1;
            int t2 = __shfl_down(cs, off, 64);
            if (lane + off < 64) cs += t2;
        }
        int ctot = __shfl(cs, 0, 64);
        as += ctot;                       // a-suffix includes whole c-half
        if (lane == 0) wtot[wv] = as;     // total of this wave's 128 bins
        __syncthreads();
        if (wv == 0 && lane < 16) {
            int v = wtot[lane];
            #pragma unroll
            for (int off = 1; off < 16; off <<= 1) {
                int t1 = __shfl_down(v, off, 64);
                if (lane + off < 16) v += t1;
            }
            wcarry[lane] = v - wtot[lane];   // exclusive suffix over higher waves
        }
        __syncthreads();
        int carry = wcarry[wv];
        hist[base + lane] = as + carry;
        hist[base + 64 + lane] = cs + carry;
    }
    __syncthreads();
    if (target > 0) {
        for (int t = tid; t < 2048; t += 1024) {
            int c = hist[t];
            int cn = (t < 2047) ? hist[t + 1] : 0;
            if (c >= target && cn < target) { spiv1 = t; sabove = cn; }
        }
    }
    __syncthreads();
    int piv1 = spiv1;
    int target2 = target - sabove;
    hist[tid] = 0; hist[tid + 1024] = 0;
    __syncthreads();
    for (int i = tid; i < m; i += 1024) {
        unsigned long long k = cb[i];
        if (((int)(k >> 53) & 0x7FF) == piv1)
            atomicAdd(&hist[(int)(k >> 42) & 0x7FF], 1);
    }
    __syncthreads();
    // ---- second suffix sum, same wave-hierarchical scheme ----
    {
        int base = wv * 128;
        int a = hist[base + lane];
        int c = hist[base + 64 + lane];
        int as = a, cs = c;
        #pragma unroll
        for (int off = 1; off < 64; off <<= 1) {
            int t1 = __shfl_down(as, off, 64);
            if (lane + off < 64) as += t1;
            int t2 = __shfl_down(cs, off, 64);
            if (lane + off < 64) cs += t2;
        }
        int ctot = __shfl(cs, 0, 64);
        as += ctot;
        if (lane == 0) wtot[wv] = as;
        __syncthreads();
        if (wv == 0 && lane < 16) {
            int v = wtot[lane];
            #pragma unroll
            for (int off = 1; off < 16; off <<= 1) {
                int t1 = __shfl_down(v, off, 64);
                if (lane + off < 16) v += t1;
            }
            wcarry[lane] = v - wtot[lane];
        }
        __syncthreads();
        int carry = wcarry[wv];
        hist[base + lane] = as + carry;
        hist[base + 64 + lane] = cs + carry;
    }
    __syncthreads();
    if (target > 0) {
        for (int t = tid; t < 2048; t += 1024) {
            int c = hist[t];
            int cn = (t < 2047) ? hist[t + 1] : 0;
            if (c >= target2 && cn < target2) spiv2 = t;
        }
    }
    __syncthreads();
    int piv2 = spiv2;
    for (int i = tid; i < m; i += 1024) {
        unsigned long long k = cb[i];
        int b1 = (int)(k >> 53) & 0x7FF;
        bool sel = (target > 0) &&
                   (b1 > piv1 || (b1 == piv1 && (((int)(k >> 42) & 0x7FF) >= piv2)));
        if (sel) {
            int p = atomicAdd(&scnt, 1);
            if (p < 4096) buf[p] = k;
        }
    }
    __syncthreads();
    int sc_ = scnt; if (sc_ > 4096) sc_ = 4096;
    int ns = 1024; while (ns < sc_) ns <<= 1;
    for (int t = tid; t < ns; t += 1024) if (t >= sc_) buf[t] = 0ULL;
    __syncthreads();
    // ---- hybrid bitonic sort, descending ----
    // Stages k=2..64 run entirely in registers per 64-elem segment (shfl_xor).
    int nseg = ns >> 6;
    for (int seg = wv; seg < nseg; seg += 16) {
        int e = (seg << 6) + lane;
        unsigned long long v = buf[e];
        #pragma unroll
        for (int k = 2; k <= 64; k <<= 1) {
            #pragma unroll
            for (int j = k >> 1; j >= 1; j >>= 1) {
                unsigned long long p = __shfl_xor(v, j, 64);
                bool upper = (lane & j) != 0;
                bool dird = ((e & k) == 0);          // descending run
                bool keepmax = (dird != upper);
                v = keepmax ? (v > p ? v : p) : (v < p ? v : p);
            }
        }
        buf[e] = v;
    }
    // Stages k>=128: LDS passes for j>=64, fused shuffle tail for j<=32.
    for (int k = 128; k <= ns; k <<= 1) {
        for (int j = k >> 1; j >= 64; j >>= 1) {
            __syncthreads();
            for (int t = tid; t < ns; t += 1024) {
                int ixj = t ^ j;
                if (ixj > t) {
                    unsigned long long a = buf[t], bb = buf[ixj];
                    if (((t & k) == 0) ? (a < bb) : (a > bb)) { buf[t] = bb; buf[ixj] = a; }
                }
            }
        }
        __syncthreads();
        for (int seg = wv; seg < nseg; seg += 16) {
            int e = (seg << 6) + lane;
            unsigned long long v = buf[e];
            #pragma unroll
            for (int j = 32; j >= 1; j >>= 1) {
                unsigned long long p = __shfl_xor(v, j, 64);
                bool upper = (lane & j) != 0;
                bool dird = ((e & k) == 0);
                bool keepmax = (dird != upper);
                v = keepmax ? (v > p ? v : p) : (v < p ? v : p);
            }
            buf[e] = v;
        }
    }
    __syncthreads();
    unsigned long long key = buf[tid];
    float kx, ky, sc;
    unsigned idx;
    if (key != 0ULL) {
        unsigned ord = (unsigned)(key >> 32);
        sc = __uint_as_float(ord ^ 0x80000000u);
        idx = 0xFFFFFFFFu - (unsigned)(key & 0xFFFFFFFFu);
        kx = (float)(idx % W);
        ky = (float)(idx / W);
    } else {
        sc = -1.0f; idx = 0; kx = 0.0f; ky = 0.0f;
    }
    int bn = b * NKP + tid;
    out[bn * 2 + 0] = kx;
    out[bn * 2 + 1] = ky;
    out[B * NKP * 2 + bn] = sc;
    fidx[bn] = (int)idx;
    __syncthreads();
    // ---- spatial perm via counting sort; wave-hierarchical prefix (4 barriers) ----
    if (tid < 512) { hist[tid] = 0; hist[tid + 1024] = 0; }
    __syncthreads();
    int bucket = (int)(idx >> 10);          // < 300
    atomicAdd(&hist[bucket], 1);
    __syncthreads();
    int iv = 0;
    if (wv < 8) {
        iv = hist[wv * 64 + lane];
        #pragma unroll
        for (int off = 1; off < 64; off <<= 1) {
            int t1 = __shfl_up(iv, off, 64);
            if (lane >= off) iv += t1;
        }
        if (lane == 63) wtot[wv] = iv;      // wave total (inclusive prefix at end)
    }
    __syncthreads();
    if (wv == 0 && lane < 8) {
        int v = wtot[lane], iv2 = v;
        #pragma unroll
        for (int off = 1; off < 8; off <<= 1) {
            int t1 = __shfl_up(iv2, off, 64);
            if (lane >= off) iv2 += t1;
        }
        wcarry[lane] = iv2 - v;             // exclusive prefix over lower waves
    }
    __syncthreads();
    if (wv < 8) hist[512 + wv * 64 + lane] = iv + wcarry[wv];   // inclusive prefix
    __syncthreads();
    int intra = atomicAdd(&hist[1024 + bucket], 1);
    int pos = hist[512 + bucket] - hist[bucket] + intra;        // exclusive base + slot
    perm[b * NKP + pos] = tid;
}

// ===== sample_all: wave-per-keypoint; seg3 NHWC d4T; seg2 NHWC cDaT when present =====
__global__ __launch_bounds__(256) void sample_all(const float* __restrict__ d1,
                                                  const float* __restrict__ d2,
                                                  const float* __restrict__ cDa,
                                                  const float* __restrict__ d4T,
                                                  const float* __restrict__ cDaT,
                                                  const int* __restrict__ fidx,
                                                  const int* __restrict__ perm,
                                                  short* __restrict__ X) {
    int lane = threadIdx.x & 63;
    int wv = threadIdx.x >> 6;
    int seg = blockIdx.y;
    int bid = blockIdx.x;
    int swz = ((bid & 7) << 7) | (bid >> 3);
    int b = swz >> 8;                  // 256 chunks per batch
    int g0 = ((swz & 255) << 2) + wv;  // kp slot within batch

    const float* map; int h, w, s, C, base, nset;
    if (seg == 0)      { map = d1;  h = 240; w = 320; s = 2;  C = 64;  base = 0;   nset = 1; }
    else if (seg == 1) { map = d2;  h = 120; w = 160; s = 4;  C = 128; base = 64;  nset = 2; }
    else if (seg == 2) { map = cDa; h = 60;  w = 80;  s = 8;  C = 256; base = 192; nset = 4; }
    else               { map = d4T; h = 30;  w = 40;  s = 16; C = 256; base = 448; nset = 4; }

    int col = (b << 10) | perm[(b << 10) + g0];
    int idx = fidx[col];
    float kx = (float)(idx % W);
    float ky = (float)(idx / W);
    float kxs = kx - (float)s * 0.5f + 0.5f;
    float kys = ky - (float)s * 0.5f + 0.5f;
    float gx = kxs / (float)(w * s - 1) * 2.0f - 1.0f;
    float gy = kys / (float)(h * s - 1) * 2.0f - 1.0f;
    float x = (gx + 1.0f) * 0.5f * (float)(w - 1);
    float y = (gy + 1.0f) * 0.5f * (float)(h - 1);
    float x0f = floorf(x), y0f = floorf(y);
    int x0 = (int)x0f, y0 = (int)y0f;
    float wx1 = x - x0f, wy1 = y - y0f;
    float wx0 = 1.0f - wx1, wy0 = 1.0f - wy1;
    bool vx0 = (x0 >= 0) && (x0 < w);
    bool vx1 = (x0 + 1 >= 0) && (x0 + 1 < w);
    bool vy0 = (y0 >= 0) && (y0 < h);
    bool vy1 = (y0 + 1 >= 0) && (y0 + 1 < h);
    int xc0 = min(max(x0, 0), w - 1), xc1 = min(max(x0 + 1, 0), w - 1);
    int yc0 = min(max(y0, 0), h - 1), yc1 = min(max(y0 + 1, 0), h - 1);
    float w00 = (vx0 && vy0) ? wx0 * wy0 : 0.0f;
    float w01 = (vx1 && vy0) ? wx1 * wy0 : 0.0f;
    float w10 = (vx0 && vy1) ? wx0 * wy1 : 0.0f;
    float w11 = (vx1 && vy1) ? wx1 * wy1 : 0.0f;

    bool nhwc = (seg == 3) || (seg == 2 && cDaT != nullptr);
    float vals[4];
    float r = 0.0f;
    if (nhwc) {
        const float* pt;
        int wq;
        if (seg == 3) { pt = d4T + ((size_t)b * 1200) * 256 + lane; wq = 40; }
        else          { pt = cDaT + ((size_t)b * 4800) * 256 + lane; wq = 80; }
        size_t o00 = ((size_t)(yc0 * wq + xc0)) << 8;
        size_t o01 = ((size_t)(yc0 * wq + xc1)) << 8;
        size_t o10 = ((size_t)(yc1 * wq + xc0)) << 8;
        size_t o11 = ((size_t)(yc1 * wq + xc1)) << 8;
        float q00[4], q01[4], q10[4], q11[4];
        #pragma unroll
        for (int j = 0; j < 4; ++j) {
            q00[j] = pt[o00 + j * 64]; q01[j] = pt[o01 + j * 64];
            q10[j] = pt[o10 + j * 64]; q11[j] = pt[o11 + j * 64];
        }
        #pragma unroll
        for (int j = 0; j < 4; ++j) {
            vals[j] = q00[j] * w00 + q01[j] * w01 + q10[j] * w10 + q11[j] * w11;
            r += vals[j] * vals[j];
        }
    } else {
        int xb = min(xc0, w - 2);
        float s0 = (xc0 == xb) ? 1.0f : 0.0f;
        float s1 = (xc1 == xb) ? 1.0f : 0.0f;
        float ax = w00 * s0 + w01 * s1;
        float ay = w00 * (1.0f - s0) + w01 * (1.0f - s1);
        float bx = w10 * s0 + w11 * s1;
        float by = w10 * (1.0f - s0) + w11 * (1.0f - s1);
        size_t hw = (size_t)(h * w);
        const float* pb = map + ((size_t)b * C + lane) * hw;
        size_t off0 = (size_t)yc0 * w + xb;
        size_t off1 = (size_t)yc1 * w + xb;
        size_t cstr = hw << 6;   // 64 channel-planes
        f2u q0[4], q1[4];
        #pragma unroll
        for (int j = 0; j < 4; ++j) {
            if (j < nset) {
                const float* p = pb + (size_t)j * cstr;
                q0[j] = *(const f2u*)(p + off0);
                q1[j] = *(const f2u*)(p + off1);
            }
        }
        #pragma unroll
        for (int j = 0; j < 4; ++j) {
            if (j < nset) {
                vals[j] = q0[j].x * ax + q0[j].y * ay + q1[j].x * bx + q1[j].y * by;
                r += vals[j] * vals[j];
            }
        }
    }
    #pragma unroll
    for (int off = 32; off > 0; off >>= 1) r += __shfl_xor(r, off, 64);
    float denom = fmaxf(sqrtf(r), 1e-12f);
    float inv = 1.0f / denom;
    short* xp = X + (size_t)col * KTOT + base + lane;
    #pragma unroll
    for (int j = 0; j < 4; ++j) {
        if (j < nset) xp[j * 64] = f2bf(vals[j] * inv);
    }
}

// ===== GEMM (bf16 MFMA): out[256,4096] = Mw[256,704] * X^T + bias; bf16 inputs =====
__global__ __launch_bounds__(256) void gemm_mfma(const short* __restrict__ Mw,
                                                 const short* __restrict__ X,
                                                 const float* __restrict__ biasf,
                                                 float* __restrict__ out) {
    __shared__ short As[64 * 72];
    __shared__ short Bs[64 * 72];
    int tid = threadIdx.x;
    int lane = tid & 63, w = tid >> 6;
    int r = lane & 15, quad = lane >> 4;
    int rowBase = blockIdx.y * 64, colBase = blockIdx.x * 64;
    int sm = tid >> 2, skq = (tid & 3) << 4;   // 16 shorts (32B) per thread per tile

    const short* pa = Mw + (size_t)(rowBase + sm) * KTOT + skq;
    const short* pb = X + (size_t)(colBase + sm) * KTOT + skq;
    s8v a0 = *(const s8v*)(pa), a1 = *(const s8v*)(pa + 8);
    s8v b0 = *(const s8v*)(pb), b1 = *(const s8v*)(pb + 8);

    f4v acc[4];
    #pragma unroll
    for (int t = 0; t < 4; ++t) acc[t] = (f4v)0.0f;

    for (int kt = 0; kt < 11; ++kt) {
        __syncthreads();
        *(s8v*)&As[sm * 72 + skq + 0] = a0;
        *(s8v*)&As[sm * 72 + skq + 8] = a1;
        *(s8v*)&Bs[sm * 72 + skq + 0] = b0;
        *(s8v*)&Bs[sm * 72 + skq + 8] = b1;
        __syncthreads();
        if (kt < 10) {
            pa += 64; pb += 64;
            a0 = *(const s8v*)(pa); a1 = *(const s8v*)(pa + 8);
            b0 = *(const s8v*)(pb); b1 = *(const s8v*)(pb + 8);
        }
        #pragma unroll
        for (int kk = 0; kk < 2; ++kk) {
            int aoff = (w * 16 + r) * 72 + kk * 32 + quad * 8;
            s8v af = *(const s8v*)&As[aoff];
            #pragma unroll
            for (int t = 0; t < 4; ++t) {
                int boff = (t * 16 + r) * 72 + kk * 32 + quad * 8;
                s8v bf = *(const s8v*)&Bs[boff];
                acc[t] = __builtin_amdgcn_mfma_f32_16x16x32_bf16(af, bf, acc[t], 0, 0, 0);
            }
        }
    }
    #pragma unroll
    for (int t = 0; t < 4; ++t) {
        int colg = colBase + t * 16 + r;
        size_t obase = (size_t)(colg >> 10) * (256 * NKP) + (size_t)(colg & 1023);
        #pragma unroll
        for (int reg = 0; reg < 4; ++reg) {
            int row = rowBase + w * 16 + quad * 4 + reg;
            out[obase + (size_t)row * NKP] = acc[t][reg] + biasf[row];
        }
    }
}

// ================= launch =================
extern "C" void kernel_launch(void* const* d_in, const int* in_sizes, int n_in,
                              void* d_out, int out_size, void* d_ws, size_t ws_size,
                              hipStream_t stream) {
    const float* scores  = (const float*)d_in[0];
    const float* d1      = (const float*)d_in[1];
    const float* d2      = (const float*)d_in[2];
    const float* cDa     = (const float*)d_in[3];
    const float* d4      = (const float*)d_in[4];
    const float* lin0_w  = (const float*)d_in[5];
    const float* lin0_b  = (const float*)d_in[6];
    const float* lin1_w  = (const float*)d_in[7];
    const float* lin1_b  = (const float*)d_in[8];
    const float* lin2_w  = (const float*)d_in[9];
    const float* lin2_b  = (const float*)d_in[10];
    const float* merge_w = (const float*)d_in[11];
    const float* merge_b = (const float*)d_in[12];
    float* out = (float*)d_out;

    char* ws = (char*)d_ws;
    short* Xbuf = (short*)ws;                                          // 5.77 MB
    float* d4T  = (float*)(ws + 6291456);                              // 4,915,200 B
    unsigned long long* cand  = (unsigned long long*)(ws + 14745600);  // 524,288 B
    int* cnt                  = (int*)(ws + 15269888);                 // 1,024 B
    int* fidx                 = (int*)(ws + 15401984);                 // 16,384 B
    short* Mw                 = (short*)(ws + 15418368);               // 360,448 B (bf16)
    float* biasf              = (float*)(ws + 16139264);               // 1,024 B
    int* perm                 = (int*)(ws + 16140288);                 // 16,384 B
    // cDaT (19,660,800 B) lives past the legacy 16.16 MB layout if ws allows.
    float* cDaT = nullptr;
    if (ws_size >= 16156672ULL + 19660800ULL)
        cDaT = (float*)(ws + 16156672);

    dim3 tgrid(W / 32, H / 32, B);   // (20,15,4)

    fuse_w<<<dim3(11, 256), 256, 0, stream>>>(merge_w, lin0_w, lin1_w, lin2_w, Mw);
    fuse_bias<<<64, 256, 0, stream>>>(merge_w, merge_b, lin0_b, lin1_b, lin2_b, biasf, cnt);
    transpose_d4<<<dim3(19, 4, 4), 256, 0, stream>>>(d4, d4T);
    if (cDaT)
        transpose_cDa<<<dim3(75, 4, 4), 256, 0, stream>>>(cDa, cDaT);
    nms_fused<<<tgrid, 512, 0, stream>>>(scores, cand, cnt);
    topk<<<B, 1024, 0, stream>>>(cand, cnt, out, fidx, perm);
    sample_all<<<dim3(1024, 4), 256, 0, stream>>>(d1, d2, cDa, d4T, cDaT, fidx, perm, Xbuf);
    gemm_mfma<<<dim3(NCOL / 64, 256 / 64), 256, 0, stream>>>(Mw, Xbuf, biasf, out + B * NKP * 3);
}

// Round 16
// 288.843 us; speedup vs baseline: 1.0504x; 1.0278x over previous
//
#include <hip/hip_runtime.h>
#include <hip/hip_bf16.h>

#define B 4
#define H 480
#define W 640
#define HW (H*W)
#define BHW (B*H*W)
#define NKP 1024
#define THRESH 0.005f
#define CAP 16384
#define NCOL (B*NKP)
#define KTOT 704

typedef __attribute__((ext_vector_type(8))) short s8v;
typedef __attribute__((ext_vector_type(4))) float f4v;
typedef struct { float x, y; } __attribute__((aligned(4))) f2u;   // 4B-aligned pair load

__device__ __forceinline__ short f2bf(float f) {
    __hip_bfloat16 h = __float2bfloat16(f);
    return *(short*)&h;
}

__device__ __forceinline__ float max3f(float a, float b, float c) {
    return fmaxf(fmaxf(a, b), c);     // clang fuses to v_max3_f32
}
// 9-wide max over a REGISTER window (compile-time base k after unroll)
#define MAX9R(v, k) \
    max3f(max3f((v)[(k)], (v)[(k)+1], (v)[(k)+2]), \
          max3f((v)[(k)+3], (v)[(k)+4], (v)[(k)+5]), \
          max3f((v)[(k)+6], (v)[(k)+7], (v)[(k)+8]))

// ===== fuse_w: Mw[256,704] weight fold; block=(64 cols x 4 K-slice waves) =====
__global__ __launch_bounds__(256) void fuse_w(const float* __restrict__ merge_w,
                                              const float* __restrict__ lin0_w,
                                              const float* __restrict__ lin1_w,
                                              const float* __restrict__ lin2_w,
                                              short* __restrict__ Mw) {
    __shared__ float red[4][64];
    int lane = threadIdx.x & 63;
    int wv = threadIdx.x >> 6;
    int jb = blockIdx.x;           // 0..10
    int o = blockIdx.y;            // 0..255
    int j = jb * 64 + lane;
    const float* mwr = merge_w + (size_t)o * KTOT;

    if (jb >= 3 && jb <= 6) {      // cols 192..447: pure copy
        if (wv == 0) Mw[(size_t)o * KTOT + j] = f2bf(mwr[j]);
        return;
    }
    float acc = 0.0f;
    if (jb == 0) {                 // K=64, slice 16/wave
        int k0 = wv * 16;
        #pragma unroll
        for (int k = 0; k < 16; ++k)
            acc += mwr[k0 + k] * lin2_w[(k0 + k) * 64 + lane];
    } else if (jb <= 2) {          // K=128, slice 32/wave
        int jj = (jb - 1) * 64 + lane;
        int k0 = wv * 32;
        #pragma unroll
        for (int k = 0; k < 32; ++k)
            acc += mwr[64 + k0 + k] * lin1_w[(k0 + k) * 128 + jj];
    } else {                       // jb 7..10: K=256, slice 64/wave
        int jj = (jb - 7) * 64 + lane;
        int k0 = wv * 64;
        #pragma unroll
        for (int k = 0; k < 64; ++k)
            acc += mwr[448 + k0 + k] * lin0_w[(k0 + k) * 256 + jj];
    }
    red[wv][lane] = acc;
    __syncthreads();
    if (wv == 0) {
        float t = red[0][lane] + red[1][lane] + red[2][lane] + red[3][lane];
        Mw[(size_t)o * KTOT + j] = f2bf(t);
    }
}

// ===== fuse_bias: biasf[256] via wave-per-row shuffle reduce; zeroes cnt =====
__global__ __launch_bounds__(256) void fuse_bias(const float* __restrict__ merge_w,
                                                 const float* __restrict__ merge_b,
                                                 const float* __restrict__ lin0_b,
                                                 const float* __restrict__ lin1_b,
                                                 const float* __restrict__ lin2_b,
                                                 float* __restrict__ biasf,
                                                 int* __restrict__ cnt) {
    int lane = threadIdx.x & 63;
    int wv = threadIdx.x >> 6;
    int o = blockIdx.x * 4 + wv;
    if (blockIdx.x == 0 && threadIdx.x < 4) cnt[threadIdx.x * 64] = 0;
    const float* mwr = merge_w + (size_t)o * KTOT;
    float acc = 0.0f;
    #pragma unroll
    for (int i = 0; i < 11; ++i) {
        int k = i * 64 + lane;
        float c;
        if (k < 64) c = lin2_b[k];
        else if (k < 192) c = lin1_b[k - 64];
        else if (k < 448) c = 0.0f;
        else c = lin0_b[k - 448];
        acc += mwr[k] * c;
    }
    #pragma unroll
    for (int off = 32; off > 0; off >>= 1) acc += __shfl_xor(acc, off, 64);
    if (lane == 0) biasf[o] = merge_b[o] + acc;
}

// ===== transpose_d4: d4 [B][256][30][40] -> d4T [B][1200][256] (f32, exact) =====
__global__ __launch_bounds__(256) void transpose_d4(const float* __restrict__ d4,
                                                    float* __restrict__ d4T) {
    __shared__ float T[64][65];
    int b = blockIdx.z;
    int p0 = blockIdx.x * 64;   // pixel tile (19 tiles over 1200)
    int c0 = blockIdx.y * 64;   // channel tile (4 tiles over 256)
    for (int t = threadIdx.x; t < 4096; t += 256) {
        int ch = t >> 6, px = t & 63;            // px fast -> coalesced read
        int gp = p0 + px;
        if (gp < 1200)
            T[ch][px] = d4[((size_t)(b * 256 + c0 + ch)) * 1200 + gp];
    }
    __syncthreads();
    for (int t = threadIdx.x; t < 4096; t += 256) {
        int px = t >> 6, ch = t & 63;            // ch fast -> coalesced write
        int gp = p0 + px;
        if (gp < 1200)
            d4T[((size_t)(b * 1200 + gp)) * 256 + c0 + ch] = T[ch][px];
    }
}

// ===== transpose_cDa: cDa [B][256][60][80] -> cDaT [B][4800][256] (f32, exact) =====
__global__ __launch_bounds__(256) void transpose_cDa(const float* __restrict__ cDa,
                                                     float* __restrict__ cDaT) {
    __shared__ float T[64][65];
    int b = blockIdx.z;
    int p0 = blockIdx.x * 64;   // pixel tile (75 tiles over 4800, exact)
    int c0 = blockIdx.y * 64;   // channel tile (4 tiles over 256)
    for (int t = threadIdx.x; t < 4096; t += 256) {
        int ch = t >> 6, px = t & 63;            // px fast -> coalesced read
        T[ch][px] = cDa[((size_t)(b * 256 + c0 + ch)) * 4800 + p0 + px];
    }
    __syncthreads();
    for (int t = threadIdx.x; t < 4096; t += 256) {
        int px = t >> 6, ch = t & 63;            // ch fast -> coalesced write
        cDaT[((size_t)(b * 4800 + p0 + px)) * 256 + c0 + ch] = T[ch][px];
    }
}

// ===== nms_fused: register sliding-window pool passes (LDS reads ~4x down) =====
__global__ __launch_bounds__(512) void nms_fused(const float* __restrict__ scores,
                                                 unsigned long long* __restrict__ cand,
                                                 int* __restrict__ cnt) {
    __shared__ float S72[72 * 72];
    __shared__ float T72[72 * 64];
    __shared__ float Mm[64 * 64];
    __shared__ float Zm[56 * 56];
    __shared__ int lcnt, gbase;
    int bz = blockIdx.z;
    int x0 = blockIdx.x * 32, y0 = blockIdx.y * 32;
    const float* sp = scores + bz * HW;
    int tid = threadIdx.x;
    int cc = tid & 63, rb = tid >> 6;   // column lane + row-block for V-passes
    if (tid == 0) lcnt = 0;
    for (int t = tid; t < 5184; t += 512) {
        int i = t / 72, j = t - i * 72;
        int gy = y0 - 20 + i, gx = x0 - 20 + j;
        S72[t] = (gy >= 0 && gy < H && gx >= 0 && gx < W) ? sp[gy * W + gx] : -1.0f;
    }
    __syncthreads();
    // P1 (H): T72[i][c] = max9(S72[i][c..c+8]), i<72, c<64; units (i, 8-col chunk)
    for (int u = tid; u < 576; u += 512) {
        int i = u >> 3, c0 = (u & 7) << 3;
        float v[16];
        #pragma unroll
        for (int k = 0; k < 16; ++k) v[k] = S72[i * 72 + c0 + k];
        #pragma unroll
        for (int k = 0; k < 8; ++k) T72[i * 64 + c0 + k] = MAX9R(v, k);
    }
    __syncthreads();
    // P2 (V+cmp): Mm[r][c] = (S==pool9), r<64, c<64; thread=(c, 8-row run)
    {
        int r0 = rb * 8;
        float v[16];
        #pragma unroll
        for (int d = 0; d < 16; ++d) v[d] = T72[(r0 + d) * 64 + cc];
        #pragma unroll
        for (int k = 0; k < 8; ++k) {
            int r = r0 + k;
            float m = MAX9R(v, k);
            float s = S72[(r + 4) * 72 + cc + 4];
            int gy = y0 - 16 + r, gx = x0 - 16 + cc;
            Mm[r * 64 + cc] = (gy >= 0 && gy < H && gx >= 0 && gx < W && s == m) ? 1.0f : 0.0f;
        }
    }
    __syncthreads();
    float* Tm = T72;
    // P3 (H): Tm[i][c] = max9(Mm[i][c..c+8]), i<64, c<56; units (i, 7 chunks)
    if (tid < 448) {
        int i = tid / 7, c0 = (tid - i * 7) << 3;
        float v[16];
        #pragma unroll
        for (int k = 0; k < 16; ++k) v[k] = Mm[i * 64 + c0 + k];
        #pragma unroll
        for (int k = 0; k < 8; ++k) Tm[i * 56 + c0 + k] = MAX9R(v, k);
    }
    __syncthreads();
    // P4 (V): Zm[i][j] = supp ? -1 : S, i<56, j<56; thread=(j<56, 7-row run)
    if (cc < 56) {
        int r0 = rb * 7;
        float v[15];
        #pragma unroll
        for (int d = 0; d < 15; ++d) v[d] = Tm[(r0 + d) * 56 + cc];
        #pragma unroll
        for (int k = 0; k < 7; ++k) {
            int i = r0 + k;
            float m = MAX9R(v, k);
            Zm[i * 56 + cc] = (m > 0.0f) ? -1.0f : S72[(i + 8) * 72 + (cc + 8)];
        }
    }
    __syncthreads();
    // P5 (H): Tm[i][c] = max9(Zm[i][c..c+8]), i<56, c<48; units (i, 6 chunks)
    if (tid < 336) {
        int i = tid / 6, c0 = (tid - i * 6) << 3;
        float v[16];
        #pragma unroll
        for (int k = 0; k < 16; ++k) v[k] = Zm[i * 56 + c0 + k];
        #pragma unroll
        for (int k = 0; k < 8; ++k) Tm[i * 56 + c0 + k] = MAX9R(v, k);
    }
    __syncthreads();
    // P6 (V+merge): Mm[(r+8)][c+8] |= new-max mask, r<48, c<48; thread=(c<48, 6-row run)
    if (cc < 48) {
        int r0 = rb * 6;
        float v[14];
        #pragma unroll
        for (int d = 0; d < 14; ++d) v[d] = Tm[(r0 + d) * 56 + cc];
        #pragma unroll
        for (int k = 0; k < 6; ++k) {
            int r = r0 + k;
            float m = MAX9R(v, k);
            float Zc = Zm[(r + 4) * 56 + cc + 4];
            int mi = (r + 8) * 64 + cc + 8;
            bool nm = (Zc == m) && (Zc >= 0.0f);
            Mm[mi] = (Mm[mi] != 0.0f || nm) ? 1.0f : 0.0f;
        }
    }
    __syncthreads();
    // P7 (H): Tm[r][c] = max9(Mm[r+8][c+8..c+16]), r<48, c<40; units (r, 5 chunks)
    if (tid < 240) {
        int r = tid / 5, c0 = (tid - r * 5) << 3;
        float v[16];
        #pragma unroll
        for (int k = 0; k < 16; ++k) v[k] = Mm[(r + 8) * 64 + 8 + c0 + k];
        #pragma unroll
        for (int k = 0; k < 8; ++k) Tm[r * 56 + c0 + k] = MAX9R(v, k);
    }
    __syncthreads();
    // P8 (V): Zm[(r+8)][c+8] = supp ? -1 : S, r<40, c<40; thread=(c<40, 5-row run)
    if (cc < 40) {
        int r0 = rb * 5;
        float v[13];
        #pragma unroll
        for (int d = 0; d < 13; ++d) v[d] = Tm[(r0 + d) * 56 + cc];
        #pragma unroll
        for (int k = 0; k < 5; ++k) {
            int r = r0 + k;
            float m = MAX9R(v, k);
            int zi = (r + 8) * 56 + cc + 8;
            Zm[zi] = (m > 0.0f) ? -1.0f : S72[(r + 16) * 72 + (cc + 16)];
        }
    }
    __syncthreads();
    // P9 (H): Tm[r][c] = max9(Zm[r+8][c+8..c+16]), r<40, c<32; units (r, 4 chunks)
    if (tid < 160) {
        int r = tid >> 2, c0 = (tid & 3) << 3;
        float v[16];
        #pragma unroll
        for (int k = 0; k < 16; ++k) v[k] = Zm[(r + 8) * 56 + 8 + c0 + k];
        #pragma unroll
        for (int k = 0; k < 8; ++k) Tm[r * 56 + c0 + k] = MAX9R(v, k);
    }
    __syncthreads();
    // P10 (V+final): r3<32, c<32; thread=(c<32, 4-row run)
    unsigned long long keys[4];
    int nl = 0;
    if (cc < 32) {
        int r0 = rb * 4;
        float v[12];
        #pragma unroll
        for (int d = 0; d < 12; ++d) v[d] = Tm[(r0 + d) * 56 + cc];
        #pragma unroll
        for (int k = 0; k < 4; ++k) {
            int r3 = r0 + k;
            float m = MAX9R(v, k);
            float Zc = Zm[(r3 + 12) * 56 + cc + 12];
            bool fin = (Mm[(r3 + 16) * 64 + cc + 16] != 0.0f) || ((Zc == m) && (Zc >= 0.0f));
            int gy = y0 + r3, gx = x0 + cc;
            float sc = S72[(r3 + 20) * 72 + (cc + 20)];
            if (fin && gy >= 4 && gy < H - 4 && gx >= 4 && gx < W - 4 && sc > THRESH) {
                unsigned r = (unsigned)(gy * W + gx);
                unsigned bits = __float_as_uint(sc) | 0x80000000u;
                keys[nl++] = ((unsigned long long)bits << 32) |
                             (unsigned long long)(0xFFFFFFFFu - r);
            }
        }
    }
    int lpos = 0;
    if (nl) lpos = atomicAdd(&lcnt, nl);
    __syncthreads();
    if (tid == 0) gbase = (lcnt > 0) ? atomicAdd(&cnt[bz * 64], lcnt) : 0;
    __syncthreads();
    for (int j = 0; j < nl; ++j) {
        int p = gbase + lpos + j;
        if (p < CAP) cand[(size_t)bz * CAP + p] = keys[j];
    }
}

// ===== topk: histogram select + LOW-BARRIER scans + hybrid shuffle bitonic =====
__global__ __launch_bounds__(1024) void topk(const unsigned long long* __restrict__ cand,
                                             const int* __restrict__ cnt,
                                             float* __restrict__ out, int* __restrict__ fidx,
                                             int* __restrict__ perm) {
    __shared__ int hist[2048];
    __shared__ int wtot[16], wcarry[16];
    __shared__ unsigned long long buf[4096];
    __shared__ int scnt, spiv1, spiv2, sabove;
    int b = blockIdx.x, tid = threadIdx.x;
    int lane = tid & 63, wv = tid >> 6;    // 16 waves
    int m = cnt[b * 64]; if (m > CAP) m = CAP;
    const unsigned long long* cb = cand + (size_t)b * CAP;
    int target = (m < 1024) ? m : 1024;

    hist[tid] = 0; hist[tid + 1024] = 0;
    if (tid == 0) { scnt = 0; spiv1 = 2048; spiv2 = 0; sabove = 0; }
    __syncthreads();
    for (int i = tid; i < m; i += 1024)
        atomicAdd(&hist[(int)(cb[i] >> 53) & 0x7FF], 1);
    __syncthreads();
    {
        int base = wv * 128;
        int a = hist[base + lane];
        int c = hist[base + 64 + lane];
        int as = a, cs = c;
        #pragma unroll
        for (int off = 1; off < 64; off <<= 1) {
            int t1 = __shfl_down(as, off, 64);
            if (lane + off < 64) as += t1;
            int t2 = __shfl_down(cs, off, 64);
            if (lane + off < 64) cs += t2;
        }
        int ctot = __shfl(cs, 0, 64);
        as += ctot;
        if (lane == 0) wtot[wv] = as;
        __syncthreads();
        if (wv == 0 && lane < 16) {
            int v = wtot[lane];
            #pragma unroll
            for (int off = 1; off < 16; off <<= 1) {
                int t1 = __shfl_down(v, off, 64);
                if (lane + off < 16) v += t1;
            }
            wcarry[lane] = v - wtot[lane];
        }
        __syncthreads();
        int carry = wcarry[wv];
        hist[base + lane] = as + carry;
        hist[base + 64 + lane] = cs + carry;
    }
    __syncthreads();
    if (target > 0) {
        for (int t = tid; t < 2048; t += 1024) {
            int c = hist[t];
            int cn = (t < 2047) ? hist[t + 1] : 0;
            if (c >= target && cn < target) { spiv1 = t; sabove = cn; }
        }
    }
    __syncthreads();
    int piv1 = spiv1;
    int target2 = target - sabove;
    hist[tid] = 0; hist[tid + 1024] = 0;
    __syncthreads();
    for (int i = tid; i < m; i += 1024) {
        unsigned long long k = cb[i];
        if (((int)(k >> 53) & 0x7FF) == piv1)
            atomicAdd(&hist[(int)(k >> 42) & 0x7FF], 1);
    }
    __syncthreads();
    {
        int base = wv * 128;
        int a = hist[base + lane];
        int c = hist[base + 64 + lane];
        int as = a, cs = c;
        #pragma unroll
        for (int off = 1; off < 64; off <<= 1) {
            int t1 = __shfl_down(as, off, 64);
            if (lane + off < 64) as += t1;
            int t2 = __shfl_down(cs, off, 64);
            if (lane + off < 64) cs += t2;
        }
        int ctot = __shfl(cs, 0, 64);
        as += ctot;
        if (lane == 0) wtot[wv] = as;
        __syncthreads();
        if (wv == 0 && lane < 16) {
            int v = wtot[lane];
            #pragma unroll
            for (int off = 1; off < 16; off <<= 1) {
                int t1 = __shfl_down(v, off, 64);
                if (lane + off < 16) v += t1;
            }
            wcarry[lane] = v - wtot[lane];
        }
        __syncthreads();
        int carry = wcarry[wv];
        hist[base + lane] = as + carry;
        hist[base + 64 + lane] = cs + carry;
    }
    __syncthreads();
    if (target > 0) {
        for (int t = tid; t < 2048; t += 1024) {
            int c = hist[t];
            int cn = (t < 2047) ? hist[t + 1] : 0;
            if (c >= target2 && cn < target2) spiv2 = t;
        }
    }
    __syncthreads();
    int piv2 = spiv2;
    for (int i = tid; i < m; i += 1024) {
        unsigned long long k = cb[i];
        int b1 = (int)(k >> 53) & 0x7FF;
        bool sel = (target > 0) &&
                   (b1 > piv1 || (b1 == piv1 && (((int)(k >> 42) & 0x7FF) >= piv2)));
        if (sel) {
            int p = atomicAdd(&scnt, 1);
            if (p < 4096) buf[p] = k;
        }
    }
    __syncthreads();
    int sc_ = scnt; if (sc_ > 4096) sc_ = 4096;
    int ns = 1024; while (ns < sc_) ns <<= 1;
    for (int t = tid; t < ns; t += 1024) if (t >= sc_) buf[t] = 0ULL;
    __syncthreads();
    int nseg = ns >> 6;
    for (int seg = wv; seg < nseg; seg += 16) {
        int e = (seg << 6) + lane;
        unsigned long long v = buf[e];
        #pragma unroll
        for (int k = 2; k <= 64; k <<= 1) {
            #pragma unroll
            for (int j = k >> 1; j >= 1; j >>= 1) {
                unsigned long long p = __shfl_xor(v, j, 64);
                bool upper = (lane & j) != 0;
                bool dird = ((e & k) == 0);
                bool keepmax = (dird != upper);
                v = keepmax ? (v > p ? v : p) : (v < p ? v : p);
            }
        }
        buf[e] = v;
    }
    for (int k = 128; k <= ns; k <<= 1) {
        for (int j = k >> 1; j >= 64; j >>= 1) {
            __syncthreads();
            for (int t = tid; t < ns; t += 1024) {
                int ixj = t ^ j;
                if (ixj > t) {
                    unsigned long long a = buf[t], bb = buf[ixj];
                    if (((t & k) == 0) ? (a < bb) : (a > bb)) { buf[t] = bb; buf[ixj] = a; }
                }
            }
        }
        __syncthreads();
        for (int seg = wv; seg < nseg; seg += 16) {
            int e = (seg << 6) + lane;
            unsigned long long v = buf[e];
            #pragma unroll
            for (int j = 32; j >= 1; j >>= 1) {
                unsigned long long p = __shfl_xor(v, j, 64);
                bool upper = (lane & j) != 0;
                bool dird = ((e & k) == 0);
                bool keepmax = (dird != upper);
                v = keepmax ? (v > p ? v : p) : (v < p ? v : p);
            }
            buf[e] = v;
        }
    }
    __syncthreads();
    unsigned long long key = buf[tid];
    float kx, ky, sc;
    unsigned idx;
    if (key != 0ULL) {
        unsigned ord = (unsigned)(key >> 32);
        sc = __uint_as_float(ord ^ 0x80000000u);
        idx = 0xFFFFFFFFu - (unsigned)(key & 0xFFFFFFFFu);
        kx = (float)(idx % W);
        ky = (float)(idx / W);
    } else {
        sc = -1.0f; idx = 0; kx = 0.0f; ky = 0.0f;
    }
    int bn = b * NKP + tid;
    out[bn * 2 + 0] = kx;
    out[bn * 2 + 1] = ky;
    out[B * NKP * 2 + bn] = sc;
    fidx[bn] = (int)idx;
    __syncthreads();
    if (tid < 512) { hist[tid] = 0; hist[tid + 1024] = 0; }
    __syncthreads();
    int bucket = (int)(idx >> 10);          // < 300
    atomicAdd(&hist[bucket], 1);
    __syncthreads();
    int iv = 0;
    if (wv < 8) {
        iv = hist[wv * 64 + lane];
        #pragma unroll
        for (int off = 1; off < 64; off <<= 1) {
            int t1 = __shfl_up(iv, off, 64);
            if (lane >= off) iv += t1;
        }
        if (lane == 63) wtot[wv] = iv;
    }
    __syncthreads();
    if (wv == 0 && lane < 8) {
        int v = wtot[lane], iv2 = v;
        #pragma unroll
        for (int off = 1; off < 8; off <<= 1) {
            int t1 = __shfl_up(iv2, off, 64);
            if (lane >= off) iv2 += t1;
        }
        wcarry[lane] = iv2 - v;
    }
    __syncthreads();
    if (wv < 8) hist[512 + wv * 64 + lane] = iv + wcarry[wv];
    __syncthreads();
    int intra = atomicAdd(&hist[1024 + bucket], 1);
    int pos = hist[512 + bucket] - hist[bucket] + intra;
    perm[b * NKP + pos] = tid;
}

// ===== sample_all: wave-per-keypoint; seg3 NHWC d4T; seg2 NHWC cDaT when present =====
__global__ __launch_bounds__(256) void sample_all(const float* __restrict__ d1,
                                                  const float* __restrict__ d2,
                                                  const float* __restrict__ cDa,
                                                  const float* __restrict__ d4T,
                                                  const float* __restrict__ cDaT,
                                                  const int* __restrict__ fidx,
                                                  const int* __restrict__ perm,
                                                  short* __restrict__ X) {
    int lane = threadIdx.x & 63;
    int wv = threadIdx.x >> 6;
    int seg = blockIdx.y;
    int bid = blockIdx.x;
    int swz = ((bid & 7) << 7) | (bid >> 3);
    int b = swz >> 8;                  // 256 chunks per batch
    int g0 = ((swz & 255) << 2) + wv;  // kp slot within batch

    const float* map; int h, w, s, C, base, nset;
    if (seg == 0)      { map = d1;  h = 240; w = 320; s = 2;  C = 64;  base = 0;   nset = 1; }
    else if (seg == 1) { map = d2;  h = 120; w = 160; s = 4;  C = 128; base = 64;  nset = 2; }
    else if (seg == 2) { map = cDa; h = 60;  w = 80;  s = 8;  C = 256; base = 192; nset = 4; }
    else               { map = d4T; h = 30;  w = 40;  s = 16; C = 256; base = 448; nset = 4; }

    int col = (b << 10) | perm[(b << 10) + g0];
    int idx = fidx[col];
    float kx = (float)(idx % W);
    float ky = (float)(idx / W);
    float kxs = kx - (float)s * 0.5f + 0.5f;
    float kys = ky - (float)s * 0.5f + 0.5f;
    float gx = kxs / (float)(w * s - 1) * 2.0f - 1.0f;
    float gy = kys / (float)(h * s - 1) * 2.0f - 1.0f;
    float x = (gx + 1.0f) * 0.5f * (float)(w - 1);
    float y = (gy + 1.0f) * 0.5f * (float)(h - 1);
    float x0f = floorf(x), y0f = floorf(y);
    int x0 = (int)x0f, y0 = (int)y0f;
    float wx1 = x - x0f, wy1 = y - y0f;
    float wx0 = 1.0f - wx1, wy0 = 1.0f - wy1;
    bool vx0 = (x0 >= 0) && (x0 < w);
    bool vx1 = (x0 + 1 >= 0) && (x0 + 1 < w);
    bool vy0 = (y0 >= 0) && (y0 < h);
    bool vy1 = (y0 + 1 >= 0) && (y0 + 1 < h);
    int xc0 = min(max(x0, 0), w - 1), xc1 = min(max(x0 + 1, 0), w - 1);
    int yc0 = min(max(y0, 0), h - 1), yc1 = min(max(y0 + 1, 0), h - 1);
    float w00 = (vx0 && vy0) ? wx0 * wy0 : 0.0f;
    float w01 = (vx1 && vy0) ? wx1 * wy0 : 0.0f;
    float w10 = (vx0 && vy1) ? wx0 * wy1 : 0.0f;
    float w11 = (vx1 && vy1) ? wx1 * wy1 : 0.0f;

    bool nhwc = (seg == 3) || (seg == 2 && cDaT != nullptr);
    float vals[4];
    float r = 0.0f;
    if (nhwc) {
        const float* pt;
        int wq;
        if (seg == 3) { pt = d4T + ((size_t)b * 1200) * 256 + lane; wq = 40; }
        else          { pt = cDaT + ((size_t)b * 4800) * 256 + lane; wq = 80; }
        size_t o00 = ((size_t)(yc0 * wq + xc0)) << 8;
        size_t o01 = ((size_t)(yc0 * wq + xc1)) << 8;
        size_t o10 = ((size_t)(yc1 * wq + xc0)) << 8;
        size_t o11 = ((size_t)(yc1 * wq + xc1)) << 8;
        float q00[4], q01[4], q10[4], q11[4];
        #pragma unroll
        for (int j = 0; j < 4; ++j) {
            q00[j] = pt[o00 + j * 64]; q01[j] = pt[o01 + j * 64];
            q10[j] = pt[o10 + j * 64]; q11[j] = pt[o11 + j * 64];
        }
        #pragma unroll
        for (int j = 0; j < 4; ++j) {
            vals[j] = q00[j] * w00 + q01[j] * w01 + q10[j] * w10 + q11[j] * w11;
            r += vals[j] * vals[j];
        }
    } else {
        int xb = min(xc0, w - 2);
        float s0 = (xc0 == xb) ? 1.0f : 0.0f;
        float s1 = (xc1 == xb) ? 1.0f : 0.0f;
        float ax = w00 * s0 + w01 * s1;
        float ay = w00 * (1.0f - s0) + w01 * (1.0f - s1);
        float bx = w10 * s0 + w11 * s1;
        float by = w10 * (1.0f - s0) + w11 * (1.0f - s1);
        size_t hw = (size_t)(h * w);
        const float* pb = map + ((size_t)b * C + lane) * hw;
        size_t off0 = (size_t)yc0 * w + xb;
        size_t off1 = (size_t)yc1 * w + xb;
        size_t cstr = hw << 6;   // 64 channel-planes
        f2u q0[4], q1[4];
        #pragma unroll
        for (int j = 0; j < 4; ++j) {
            if (j < nset) {
                const float* p = pb + (size_t)j * cstr;
                q0[j] = *(const f2u*)(p + off0);
                q1[j] = *(const f2u*)(p + off1);
            }
        }
        #pragma unroll
        for (int j = 0; j < 4; ++j) {
            if (j < nset) {
                vals[j] = q0[j].x * ax + q0[j].y * ay + q1[j].x * bx + q1[j].y * by;
                r += vals[j] * vals[j];
            }
        }
    }
    #pragma unroll
    for (int off = 32; off > 0; off >>= 1) r += __shfl_xor(r, off, 64);
    float denom = fmaxf(sqrtf(r), 1e-12f);
    float inv = 1.0f / denom;
    short* xp = X + (size_t)col * KTOT + base + lane;
    #pragma unroll
    for (int j = 0; j < 4; ++j) {
        if (j < nset) xp[j * 64] = f2bf(vals[j] * inv);
    }
}

// ===== GEMM (bf16 MFMA): out[256,4096] = Mw[256,704] * X^T + bias; bf16 inputs =====
__global__ __launch_bounds__(256) void gemm_mfma(const short* __restrict__ Mw,
                                                 const short* __restrict__ X,
                                                 const float* __restrict__ biasf,
                                                 float* __restrict__ out) {
    __shared__ short As[64 * 72];
    __shared__ short Bs[64 * 72];
    int tid = threadIdx.x;
    int lane = tid & 63, w = tid >> 6;
    int r = lane & 15, quad = lane >> 4;
    int rowBase = blockIdx.y * 64, colBase = blockIdx.x * 64;
    int sm = tid >> 2, skq = (tid & 3) << 4;   // 16 shorts (32B) per thread per tile

    const short* pa = Mw + (size_t)(rowBase + sm) * KTOT + skq;
    const short* pb = X + (size_t)(colBase + sm) * KTOT + skq;
    s8v a0 = *(const s8v*)(pa), a1 = *(const s8v*)(pa + 8);
    s8v b0 = *(const s8v*)(pb), b1 = *(const s8v*)(pb + 8);

    f4v acc[4];
    #pragma unroll
    for (int t = 0; t < 4; ++t) acc[t] = (f4v)0.0f;

    for (int kt = 0; kt < 11; ++kt) {
        __syncthreads();
        *(s8v*)&As[sm * 72 + skq + 0] = a0;
        *(s8v*)&As[sm * 72 + skq + 8] = a1;
        *(s8v*)&Bs[sm * 72 + skq + 0] = b0;
        *(s8v*)&Bs[sm * 72 + skq + 8] = b1;
        __syncthreads();
        if (kt < 10) {
            pa += 64; pb += 64;
            a0 = *(const s8v*)(pa); a1 = *(const s8v*)(pa + 8);
            b0 = *(const s8v*)(pb); b1 = *(const s8v*)(pb + 8);
        }
        #pragma unroll
        for (int kk = 0; kk < 2; ++kk) {
            int aoff = (w * 16 + r) * 72 + kk * 32 + quad * 8;
            s8v af = *(const s8v*)&As[aoff];
            #pragma unroll
            for (int t = 0; t < 4; ++t) {
                int boff = (t * 16 + r) * 72 + kk * 32 + quad * 8;
                s8v bf = *(const s8v*)&Bs[boff];
                acc[t] = __builtin_amdgcn_mfma_f32_16x16x32_bf16(af, bf, acc[t], 0, 0, 0);
            }
        }
    }
    #pragma unroll
    for (int t = 0; t < 4; ++t) {
        int colg = colBase + t * 16 + r;
        size_t obase = (size_t)(colg >> 10) * (256 * NKP) + (size_t)(colg & 1023);
        #pragma unroll
        for (int reg = 0; reg < 4; ++reg) {
            int row = rowBase + w * 16 + quad * 4 + reg;
            out[obase + (size_t)row * NKP] = acc[t][reg] + biasf[row];
        }
    }
}

// ================= launch =================
extern "C" void kernel_launch(void* const* d_in, const int* in_sizes, int n_in,
                              void* d_out, int out_size, void* d_ws, size_t ws_size,
                              hipStream_t stream) {
    const float* scores  = (const float*)d_in[0];
    const float* d1      = (const float*)d_in[1];
    const float* d2      = (const float*)d_in[2];
    const float* cDa     = (const float*)d_in[3];
    const float* d4      = (const float*)d_in[4];
    const float* lin0_w  = (const float*)d_in[5];
    const float* lin0_b  = (const float*)d_in[6];
    const float* lin1_w  = (const float*)d_in[7];
    const float* lin1_b  = (const float*)d_in[8];
    const float* lin2_w  = (const float*)d_in[9];
    const float* lin2_b  = (const float*)d_in[10];
    const float* merge_w = (const float*)d_in[11];
    const float* merge_b = (const float*)d_in[12];
    float* out = (float*)d_out;

    char* ws = (char*)d_ws;
    short* Xbuf = (short*)ws;                                          // 5.77 MB
    float* d4T  = (float*)(ws + 6291456);                              // 4,915,200 B
    unsigned long long* cand  = (unsigned long long*)(ws + 14745600);  // 524,288 B
    int* cnt                  = (int*)(ws + 15269888);                 // 1,024 B
    int* fidx                 = (int*)(ws + 15401984);                 // 16,384 B
    short* Mw                 = (short*)(ws + 15418368);               // 360,448 B (bf16)
    float* biasf              = (float*)(ws + 16139264);               // 1,024 B
    int* perm                 = (int*)(ws + 16140288);                 // 16,384 B
    // cDaT (19,660,800 B) lives past the legacy 16.16 MB layout if ws allows.
    float* cDaT = nullptr;
    if (ws_size >= 16156672ULL + 19660800ULL)
        cDaT = (float*)(ws + 16156672);

    dim3 tgrid(W / 32, H / 32, B);   // (20,15,4)

    fuse_w<<<dim3(11, 256), 256, 0, stream>>>(merge_w, lin0_w, lin1_w, lin2_w, Mw);
    fuse_bias<<<64, 256, 0, stream>>>(merge_w, merge_b, lin0_b, lin1_b, lin2_b, biasf, cnt);
    transpose_d4<<<dim3(19, 4, 4), 256, 0, stream>>>(d4, d4T);
    if (cDaT)
        transpose_cDa<<<dim3(75, 4, 4), 256, 0, stream>>>(cDa, cDaT);
    nms_fused<<<tgrid, 512, 0, stream>>>(scores, cand, cnt);
    topk<<<B, 1024, 0, stream>>>(cand, cnt, out, fidx, perm);
    sample_all<<<dim3(1024, 4), 256, 0, stream>>>(d1, d2, cDa, d4T, cDaT, fidx, perm, Xbuf);
    gemm_mfma<<<dim3(NCOL / 64, 256 / 64), 256, 0, stream>>>(Mw, Xbuf, biasf, out + B * NKP * 3);
}